// Round 1
// baseline (766.126 us; speedup 1.0000x reference)
//
#include <hip/hip_runtime.h>
#include <stdint.h>

#define B_ 2
#define T_ 2048
#define C_ 2048
#define H_ 16
#define D_ 128
#define KSP 64
#define C3 6144   // 3*C_

typedef __attribute__((ext_vector_type(4))) float f32x4;
typedef __attribute__((ext_vector_type(8))) _Float16 f16x8;
typedef __attribute__((ext_vector_type(4))) _Float16 f16x4;
typedef __attribute__((ext_vector_type(2))) _Float16 f16x2;

// global -> LDS async copy, 16B per lane. LDS dest is wave-uniform base + lane*16.
__device__ __forceinline__ void gload16(const void* g, void* l) {
  __builtin_amdgcn_global_load_lds(
      (__attribute__((address_space(1))) void*)(uintptr_t)g,
      (__attribute__((address_space(3))) void*)(uint32_t)(uintptr_t)l,
      16, 0, 0);
}

// ---------------- elementwise f32 -> f16 ----------------
__global__ void k_cvt(const float* __restrict__ in, _Float16* __restrict__ out, int n) {
  int i = (blockIdx.x * blockDim.x + threadIdx.x) * 4;
  if (i >= n) return;
  const float4 v = *(const float4*)(in + i);
  f16x4 o;
  o.x = (_Float16)v.x; o.y = (_Float16)v.y; o.z = (_Float16)v.z; o.w = (_Float16)v.w;
  *(f16x4*)(out + i) = o;
}

// ---------------- transpose + convert: W (K x N) f32 -> WT (N x K) f16 ----------------
__global__ void k_tconv(const float* __restrict__ W, _Float16* __restrict__ WT, int K, int N) {
  __shared__ float tile[32][33];
  const int n0 = blockIdx.x * 32, k0 = blockIdx.y * 32;
  const int tx = threadIdx.x, ty = threadIdx.y;  // 32 x 8
#pragma unroll
  for (int r = 0; r < 4; ++r)
    tile[ty + r * 8][tx] = W[(size_t)(k0 + ty + r * 8) * N + n0 + tx];
  __syncthreads();
#pragma unroll
  for (int r = 0; r < 4; ++r)
    WT[(size_t)(n0 + ty + r * 8) * K + k0 + tx] = (_Float16)tile[tx][ty + r * 8];
}

// ---------------- fp16 MFMA GEMM: C = A(MxK) * BT(NxK)^T + bias ----------------
// m97 structure: 128x128 tile, BK=32, 4 waves in 2x2 of 64x64, 16x16x32 MFMA.
template <int F16OUT>
__global__ __launch_bounds__(256) void k_gemm(const _Float16* __restrict__ A,
                                              const _Float16* __restrict__ BT,
                                              const float* __restrict__ bias,
                                              void* __restrict__ Cout,
                                              int M, int N, int K) {
  __shared__ __align__(16) _Float16 sA[128 * 32];
  __shared__ __align__(16) _Float16 sB[128 * 32];
  const int tid = threadIdx.x;
  const int lane = tid & 63;
  const int wid = tid >> 6;
  const int wr = wid >> 1, wc = wid & 1;
  const int bm = blockIdx.y, bn = blockIdx.x;
  const int lr = lane & 15;
  const int lk = (lane >> 4) << 3;
  f32x4 acc[4][4] = {};
  // staging: chunk id cid in [0,512): row = cid>>2, col8 = (cid&3)*8; flat f16 off = cid*8
  const int srow = tid >> 2, scol = (tid & 3) << 3;
  const _Float16* ag = A + (size_t)(bm * 128 + srow) * K + scol;
  const _Float16* bg = BT + (size_t)(bn * 128 + srow) * K + scol;
  _Float16* la = &sA[tid * 8];
  _Float16* lb = &sB[tid * 8];
  const int KH = 64 * K;  // +64 rows
  for (int k0 = 0; k0 < K; k0 += 32) {
    gload16(ag, la);
    gload16(ag + KH, la + 2048);
    gload16(bg, lb);
    gload16(bg + KH, lb + 2048);
    ag += 32; bg += 32;
    __syncthreads();  // drains vmcnt -> LDS tile ready
    f16x8 af[4], bf[4];
#pragma unroll
    for (int mi = 0; mi < 4; ++mi)
      af[mi] = *(const f16x8*)&sA[(wr * 64 + mi * 16 + lr) * 32 + lk];
#pragma unroll
    for (int nj = 0; nj < 4; ++nj)
      bf[nj] = *(const f16x8*)&sB[(wc * 64 + nj * 16 + lr) * 32 + lk];
#pragma unroll
    for (int mi = 0; mi < 4; ++mi)
#pragma unroll
      for (int nj = 0; nj < 4; ++nj)
        acc[mi][nj] = __builtin_amdgcn_mfma_f32_16x16x32_f16(af[mi], bf[nj], acc[mi][nj], 0, 0, 0);
    __syncthreads();  // all waves done with LDS before next overwrite
  }
  // C/D layout: row = (lane>>4)*4 + reg, col = lane&15
  const int row0 = bm * 128 + wr * 64;
  const int col0 = bn * 128 + wc * 64;
#pragma unroll
  for (int mi = 0; mi < 4; ++mi) {
#pragma unroll
    for (int nj = 0; nj < 4; ++nj) {
      const int col = col0 + nj * 16 + lr;
      const float bv = bias ? bias[col] : 0.f;
#pragma unroll
      for (int r = 0; r < 4; ++r) {
        const int row = row0 + mi * 16 + ((lane >> 4) << 2) + r;
        const float v = acc[mi][nj][r] + bv;
        if (F16OUT)
          ((_Float16*)Cout)[(size_t)row * N + col] = (_Float16)v;
        else
          ((float*)Cout)[(size_t)row * N + col] = v;
      }
    }
  }
}

// ---------------- in-place RoPE on q,k sections of qkv (B,T,3C) fp16 ----------------
__global__ void k_rope(_Float16* __restrict__ qkv) {
  const int idx = blockIdx.x * blockDim.x + threadIdx.x;  // exact grid
  const int pp = idx & 2047;   // pair slot within (b,t): [0,1024)=q, [1024,2048)=k
  const int bt = idx >> 11;
  const int t = bt & (T_ - 1);
  const int sec = pp >> 10;
  const int p = pp & 1023;
  const int hh = p >> 6;
  const int dp = p & 63;
  const float freq = expf(-0.14391156831212787f * (float)dp);  // 10000^(-dp/64)
  const float ang = (float)t * freq;
  float sn, cs;
  sincosf(ang, &sn, &cs);
  const size_t base = (size_t)bt * C3 + (size_t)sec * C_ + hh * D_ + 2 * dp;
  f16x2 v = *(f16x2*)(qkv + base);
  const float xe = (float)v.x, xo = (float)v.y;
  f16x2 o;
  o.x = (_Float16)(xe * cs - xo * sn);
  o.y = (_Float16)(xe * sn + xo * cs);
  *(f16x2*)(qkv + base) = o;
}

// ---------------- death time d[h][j]: index of 64th beater (T if <64 beaters) ----------------
__global__ void k_death(const float* __restrict__ rw, int* __restrict__ dd) {
  const int idx = blockIdx.x * blockDim.x + threadIdx.x;  // h*T + j
  const int h = idx >> 11, j = idx & (T_ - 1);
  const float* s = rw + h * T_;
  const float sj = s[j];
  int cnt = 0, d = T_;
  for (int t = 0; t < T_; ++t) {
    const float st = s[t];
    if (st > sj || (st == sj && t < j)) {
      if (++cnt == KSP) { d = t; break; }
    }
  }
  dd[idx] = d;
}

// ---------------- key lists: one wave per (h,i), ballot-compact {j<=i : d[h,j]>i} ----------------
__global__ __launch_bounds__(64) void k_lists(const int* __restrict__ dd,
                                              int* __restrict__ lst,
                                              int* __restrict__ cnt) {
  const int bid = blockIdx.x;  // h*T + i
  const int i = bid & (T_ - 1);
  const int h = bid >> 11;
  const int lane = threadIdx.x;
  const int* dh = dd + h * T_;
  int total = 0;
  for (int base = 0; base <= i; base += 64) {
    const int jx = base + lane;
    const bool pred = (jx <= i) && (dh[jx] > i);
    const unsigned long long bal = __ballot(pred);
    const int pos = total + __popcll(bal & ((1ull << lane) - 1ull));
    if (pred && pos < KSP) lst[(size_t)bid * KSP + pos] = jx;
    total += __popcll(bal);
  }
  if (lane == 0) cnt[bid] = total < KSP ? total : KSP;
}

// ---------------- sparse attention: one wave per (b,h,i) ----------------
__global__ __launch_bounds__(64) void k_attn(const _Float16* __restrict__ qkv,
                                             const int* __restrict__ lst,
                                             const int* __restrict__ cnt,
                                             _Float16* __restrict__ out) {
  const int bid = blockIdx.x;  // b*H*T + h*T + i
  const int i = bid & (T_ - 1);
  const int h = (bid >> 11) & (H_ - 1);
  const int b = bid >> 15;
  const int lane = threadIdx.x;
  const int c = cnt[(h << 11) + i];
  int j = 0;
  if (lane < c) j = lst[((size_t)((h << 11) + i)) * KSP + lane];
  // phase 1: lane = key slot; score = q . k_j / sqrt(D)
  const _Float16* qrow = qkv + (size_t)(b * T_ + i) * C3 + h * D_;
  const _Float16* krow = qkv + (size_t)(b * T_ + j) * C3 + C_ + h * D_;
  float acc = 0.f;
#pragma unroll
  for (int d8 = 0; d8 < D_ / 8; ++d8) {
    const f16x8 qv = *(const f16x8*)(qrow + d8 * 8);
    const f16x8 kv = *(const f16x8*)(krow + d8 * 8);
#pragma unroll
    for (int t = 0; t < 8; ++t) acc += (float)qv[t] * (float)kv[t];
  }
  float score = (lane < c) ? acc * 0.08838834764831845f : -INFINITY;
  float m = score;
#pragma unroll
  for (int o = 32; o; o >>= 1) m = fmaxf(m, __shfl_xor(m, o));
  const float e = (lane < c) ? expf(score - m) : 0.f;
  float ssum = e;
#pragma unroll
  for (int o = 32; o; o >>= 1) ssum += __shfl_xor(ssum, o);
  const float p = e / ssum;
  // phase 2: lane = dim pair; out_d = sum_j p_j * v[j][d]
  float o0 = 0.f, o1 = 0.f;
  for (int jj = 0; jj < c; ++jj) {
    const float pj = __shfl(p, jj);
    const int jx = __shfl(j, jj);
    const f16x2 vv = *(const f16x2*)(qkv + (size_t)(b * T_ + jx) * C3 + 2 * C_ + h * D_ + 2 * lane);
    o0 += pj * (float)vv.x;
    o1 += pj * (float)vv.y;
  }
  f16x2 ov;
  ov.x = (_Float16)o0;
  ov.y = (_Float16)o1;
  *(f16x2*)(out + (size_t)(b * T_ + i) * C_ + h * D_ + 2 * lane) = ov;
}

extern "C" void kernel_launch(void* const* d_in, const int* in_sizes, int n_in,
                              void* d_out, int out_size, void* d_ws, size_t ws_size,
                              hipStream_t stream) {
  const float* x  = (const float*)d_in[0];
  const float* Wa = (const float*)d_in[1];
  const float* ba = (const float*)d_in[2];
  const float* Wp = (const float*)d_in[3];
  const float* bp = (const float*)d_in[4];
  const float* rw = (const float*)d_in[5];

  char* ws = (char*)d_ws;
  _Float16* qkv16 = (_Float16*)(ws);                              // 48 MB
  _Float16* WaT   = (_Float16*)(ws + (size_t)48 * 1024 * 1024);   // 24 MB
  _Float16* WpT   = (_Float16*)(ws + (size_t)72 * 1024 * 1024);   //  8 MB
  _Float16* x16   = (_Float16*)(ws + (size_t)80 * 1024 * 1024);   // 16 MB (reused as att16)
  int* dd  = (int*)(ws + (size_t)96 * 1024 * 1024);               // 128 KB
  int* cn  = (int*)(ws + (size_t)96 * 1024 * 1024 + (1 << 17));   // 128 KB
  int* lst = (int*)(ws + (size_t)96 * 1024 * 1024 + (2 << 17));   //  8 MB
  _Float16* att16 = x16;  // x16 dead after GEMM1; total ws use ~104.5 MB

  // 1. x -> fp16
  k_cvt<<<dim3((B_ * T_ * C_) / 1024), dim3(256), 0, stream>>>(x, x16, B_ * T_ * C_);
  // 2. W_attn (2048 x 6144) -> WaT (6144 x 2048) fp16
  k_tconv<<<dim3(C3 / 32, C_ / 32), dim3(32, 8), 0, stream>>>(Wa, WaT, C_, C3);
  // 3. W_proj -> WpT fp16
  k_tconv<<<dim3(C_ / 32, C_ / 32), dim3(32, 8), 0, stream>>>(Wp, WpT, C_, C_);
  // 4. qkv = x @ W_attn + b_attn  (fp16 out)
  k_gemm<1><<<dim3(C3 / 128, (B_ * T_) / 128), dim3(256), 0, stream>>>(
      x16, WaT, ba, (void*)qkv16, B_ * T_, C3, C_);
  // 5. RoPE in place on q,k
  k_rope<<<dim3((B_ * T_ * 2048) / 256), dim3(256), 0, stream>>>(qkv16);
  // 6. death times
  k_death<<<dim3((H_ * T_) / 256), dim3(256), 0, stream>>>(rw, dd);
  // 7. key lists
  k_lists<<<dim3(H_ * T_), dim3(64), 0, stream>>>(dd, lst, cn);
  // 8. sparse attention -> att16 (B,T,C) fp16
  k_attn<<<dim3(B_ * H_ * T_), dim3(64), 0, stream>>>(qkv16, lst, cn, att16);
  // 9. out = att @ W_proj + b_proj (f32 out)
  k_gemm<0><<<dim3(C_ / 128, (B_ * T_) / 128), dim3(256), 0, stream>>>(
      att16, WpT, bp, d_out, B_ * T_, C_, C_);
}

// Round 2
// 519.134 us; speedup vs baseline: 1.4758x; 1.4758x over previous
//
#include <hip/hip_runtime.h>
#include <stdint.h>

#define B_ 2
#define T_ 2048
#define C_ 2048
#define H_ 16
#define D_ 128
#define KSP 64
#define C3 6144   // 3*C_

typedef __attribute__((ext_vector_type(4))) float f32x4;
typedef __attribute__((ext_vector_type(8))) _Float16 f16x8;
typedef __attribute__((ext_vector_type(4))) _Float16 f16x4;
typedef __attribute__((ext_vector_type(2))) _Float16 f16x2;

// global -> LDS async copy, 16B per lane. LDS dest is wave-uniform base + lane*16.
__device__ __forceinline__ void gload16(const void* g, void* l) {
  __builtin_amdgcn_global_load_lds(
      (__attribute__((address_space(1))) void*)(uintptr_t)g,
      (__attribute__((address_space(3))) void*)(uint32_t)(uintptr_t)l,
      16, 0, 0);
}

// ---------------- elementwise f32 -> f16 ----------------
__global__ void k_cvt(const float* __restrict__ in, _Float16* __restrict__ out, int n) {
  int i = (blockIdx.x * blockDim.x + threadIdx.x) * 4;
  if (i >= n) return;
  const float4 v = *(const float4*)(in + i);
  f16x4 o;
  o.x = (_Float16)v.x; o.y = (_Float16)v.y; o.z = (_Float16)v.z; o.w = (_Float16)v.w;
  *(f16x4*)(out + i) = o;
}

// ---------------- transpose + convert: W (K x N) f32 -> WT (N x K) f16 ----------------
__global__ void k_tconv(const float* __restrict__ W, _Float16* __restrict__ WT, int K, int N) {
  __shared__ float tile[32][33];
  const int n0 = blockIdx.x * 32, k0 = blockIdx.y * 32;
  const int tx = threadIdx.x, ty = threadIdx.y;  // 32 x 8
#pragma unroll
  for (int r = 0; r < 4; ++r)
    tile[ty + r * 8][tx] = W[(size_t)(k0 + ty + r * 8) * N + n0 + tx];
  __syncthreads();
#pragma unroll
  for (int r = 0; r < 4; ++r)
    WT[(size_t)(n0 + ty + r * 8) * K + k0 + tx] = (_Float16)tile[tx][ty + r * 8];
}

// ---------------- fp16 MFMA GEMM: C = A(MxK) * BT(NxK)^T + bias ----------------
// m97 structure: 128x128 tile, BK=32, 4 waves in 2x2 of 64x64, 16x16x32 MFMA.
template <int F16OUT>
__global__ __launch_bounds__(256) void k_gemm(const _Float16* __restrict__ A,
                                              const _Float16* __restrict__ BT,
                                              const float* __restrict__ bias,
                                              void* __restrict__ Cout,
                                              int M, int N, int K) {
  __shared__ __align__(16) _Float16 sA[128 * 32];
  __shared__ __align__(16) _Float16 sB[128 * 32];
  const int tid = threadIdx.x;
  const int lane = tid & 63;
  const int wid = tid >> 6;
  const int wr = wid >> 1, wc = wid & 1;
  const int bm = blockIdx.y, bn = blockIdx.x;
  const int lr = lane & 15;
  const int lk = (lane >> 4) << 3;
  f32x4 acc[4][4] = {};
  // staging: chunk id cid in [0,512): row = cid>>2, col8 = (cid&3)*8; flat f16 off = cid*8
  const int srow = tid >> 2, scol = (tid & 3) << 3;
  const _Float16* ag = A + (size_t)(bm * 128 + srow) * K + scol;
  const _Float16* bg = BT + (size_t)(bn * 128 + srow) * K + scol;
  _Float16* la = &sA[tid * 8];
  _Float16* lb = &sB[tid * 8];
  const int KH = 64 * K;  // +64 rows
  for (int k0 = 0; k0 < K; k0 += 32) {
    gload16(ag, la);
    gload16(ag + KH, la + 2048);
    gload16(bg, lb);
    gload16(bg + KH, lb + 2048);
    ag += 32; bg += 32;
    __syncthreads();  // drains vmcnt -> LDS tile ready
    f16x8 af[4], bf[4];
#pragma unroll
    for (int mi = 0; mi < 4; ++mi)
      af[mi] = *(const f16x8*)&sA[(wr * 64 + mi * 16 + lr) * 32 + lk];
#pragma unroll
    for (int nj = 0; nj < 4; ++nj)
      bf[nj] = *(const f16x8*)&sB[(wc * 64 + nj * 16 + lr) * 32 + lk];
#pragma unroll
    for (int mi = 0; mi < 4; ++mi)
#pragma unroll
      for (int nj = 0; nj < 4; ++nj)
        acc[mi][nj] = __builtin_amdgcn_mfma_f32_16x16x32_f16(af[mi], bf[nj], acc[mi][nj], 0, 0, 0);
    __syncthreads();  // all waves done with LDS before next overwrite
  }
  // C/D layout: row = (lane>>4)*4 + reg, col = lane&15
  const int row0 = bm * 128 + wr * 64;
  const int col0 = bn * 128 + wc * 64;
#pragma unroll
  for (int mi = 0; mi < 4; ++mi) {
#pragma unroll
    for (int nj = 0; nj < 4; ++nj) {
      const int col = col0 + nj * 16 + lr;
      const float bv = bias ? bias[col] : 0.f;
#pragma unroll
      for (int r = 0; r < 4; ++r) {
        const int row = row0 + mi * 16 + ((lane >> 4) << 2) + r;
        const float v = acc[mi][nj][r] + bv;
        if (F16OUT)
          ((_Float16*)Cout)[(size_t)row * N + col] = (_Float16)v;
        else
          ((float*)Cout)[(size_t)row * N + col] = v;
      }
    }
  }
}

// ---------------- in-place RoPE on q,k sections of qkv (B,T,3C) fp16 ----------------
__global__ void k_rope(_Float16* __restrict__ qkv) {
  const int idx = blockIdx.x * blockDim.x + threadIdx.x;  // exact grid
  const int pp = idx & 2047;   // pair slot within (b,t): [0,1024)=q, [1024,2048)=k
  const int bt = idx >> 11;
  const int t = bt & (T_ - 1);
  const int sec = pp >> 10;
  const int p = pp & 1023;
  const int hh = p >> 6;
  const int dp = p & 63;
  const float freq = expf(-0.14391156831212787f * (float)dp);  // 10000^(-dp/64)
  const float ang = (float)t * freq;
  float sn, cs;
  sincosf(ang, &sn, &cs);
  const size_t base = (size_t)bt * C3 + (size_t)sec * C_ + hh * D_ + 2 * dp;
  f16x2 v = *(f16x2*)(qkv + base);
  const float xe = (float)v.x, xo = (float)v.y;
  f16x2 o;
  o.x = (_Float16)(xe * cs - xo * sn);
  o.y = (_Float16)(xe * sn + xo * cs);
  *(f16x2*)(qkv + base) = o;
}

// ---------------- death time d[h][j]: index of 64th beater (T if <64 beaters) ----------------
// One WAVE per (h,j): ballot-based ordered count, <=32 wave-parallel steps.
__global__ __launch_bounds__(256) void k_death(const float* __restrict__ rw, int* __restrict__ dd) {
  const int widG = blockIdx.x * 4 + (threadIdx.x >> 6);  // global wave id = h*T_ + j
  const int lane = threadIdx.x & 63;
  const int h = widG >> 11, j = widG & (T_ - 1);
  const float* s = rw + h * T_;
  const float sj = s[j];
  int total = 0, d = T_;
  for (int base = 0; base < T_; base += 64) {
    const int t = base + lane;
    const float st = s[t];
    const bool beat = (st > sj) || (st == sj && t < j);
    const unsigned long long bal = __ballot(beat);
    const int c = __popcll(bal);
    if (total + c >= KSP) {  // wave-uniform condition
      const int need = KSP - total;  // 1-based rank within this chunk
      const int p = __popcll(bal & ((1ull << lane) - 1ull));
      const unsigned long long win = __ballot(beat && (p == need - 1));
      d = base + __builtin_ctzll(win);
      break;
    }
    total += c;
  }
  if (lane == 0) dd[widG] = d;
}

// ---------------- key lists: one wave per (h,i), ballot-compact {j<=i : d[h,j]>i} ----------------
__global__ __launch_bounds__(64) void k_lists(const int* __restrict__ dd,
                                              int* __restrict__ lst,
                                              int* __restrict__ cnt) {
  const int bid = blockIdx.x;  // h*T + i
  const int i = bid & (T_ - 1);
  const int h = bid >> 11;
  const int lane = threadIdx.x;
  const int* dh = dd + h * T_;
  int total = 0;
  for (int base = 0; base <= i; base += 64) {
    const int jx = base + lane;
    const bool pred = (jx <= i) && (dh[jx] > i);
    const unsigned long long bal = __ballot(pred);
    const int pos = total + __popcll(bal & ((1ull << lane) - 1ull));
    if (pred && pos < KSP) lst[(size_t)bid * KSP + pos] = jx;
    total += __popcll(bal);
  }
  if (lane == 0) cnt[bid] = total < KSP ? total : KSP;
}

// ---------------- sparse attention: one wave per (b,h,i) ----------------
__global__ __launch_bounds__(64) void k_attn(const _Float16* __restrict__ qkv,
                                             const int* __restrict__ lst,
                                             const int* __restrict__ cnt,
                                             _Float16* __restrict__ out) {
  const int bid = blockIdx.x;  // b*H*T + h*T + i
  const int i = bid & (T_ - 1);
  const int h = (bid >> 11) & (H_ - 1);
  const int b = bid >> 15;
  const int lane = threadIdx.x;
  const int c = cnt[(h << 11) + i];
  int j = 0;
  if (lane < c) j = lst[((size_t)((h << 11) + i)) * KSP + lane];
  // phase 1: lane = key slot; score = q . k_j / sqrt(D)
  const _Float16* qrow = qkv + (size_t)(b * T_ + i) * C3 + h * D_;
  const _Float16* krow = qkv + (size_t)(b * T_ + j) * C3 + C_ + h * D_;
  float acc = 0.f;
#pragma unroll
  for (int d8 = 0; d8 < D_ / 8; ++d8) {
    const f16x8 qv = *(const f16x8*)(qrow + d8 * 8);
    const f16x8 kv = *(const f16x8*)(krow + d8 * 8);
#pragma unroll
    for (int t = 0; t < 8; ++t) acc += (float)qv[t] * (float)kv[t];
  }
  float score = (lane < c) ? acc * 0.08838834764831845f : -INFINITY;
  float m = score;
#pragma unroll
  for (int o = 32; o; o >>= 1) m = fmaxf(m, __shfl_xor(m, o));
  const float e = (lane < c) ? expf(score - m) : 0.f;
  float ssum = e;
#pragma unroll
  for (int o = 32; o; o >>= 1) ssum += __shfl_xor(ssum, o);
  const float p = e / ssum;
  // phase 2: lane = dim pair; out_d = sum_j p_j * v[j][d]
  float o0 = 0.f, o1 = 0.f;
  for (int jj = 0; jj < c; ++jj) {
    const float pj = __shfl(p, jj);
    const int jx = __shfl(j, jj);
    const f16x2 vv = *(const f16x2*)(qkv + (size_t)(b * T_ + jx) * C3 + 2 * C_ + h * D_ + 2 * lane);
    o0 += pj * (float)vv.x;
    o1 += pj * (float)vv.y;
  }
  f16x2 ov;
  ov.x = (_Float16)o0;
  ov.y = (_Float16)o1;
  *(f16x2*)(out + (size_t)(b * T_ + i) * C_ + h * D_ + 2 * lane) = ov;
}

extern "C" void kernel_launch(void* const* d_in, const int* in_sizes, int n_in,
                              void* d_out, int out_size, void* d_ws, size_t ws_size,
                              hipStream_t stream) {
  const float* x  = (const float*)d_in[0];
  const float* Wa = (const float*)d_in[1];
  const float* ba = (const float*)d_in[2];
  const float* Wp = (const float*)d_in[3];
  const float* bp = (const float*)d_in[4];
  const float* rw = (const float*)d_in[5];

  char* ws = (char*)d_ws;
  _Float16* qkv16 = (_Float16*)(ws);                              // 48 MB
  _Float16* WaT   = (_Float16*)(ws + (size_t)48 * 1024 * 1024);   // 24 MB
  _Float16* WpT   = (_Float16*)(ws + (size_t)72 * 1024 * 1024);   //  8 MB
  _Float16* x16   = (_Float16*)(ws + (size_t)80 * 1024 * 1024);   // 16 MB (reused as att16)
  int* dd  = (int*)(ws + (size_t)96 * 1024 * 1024);               // 128 KB
  int* cn  = (int*)(ws + (size_t)96 * 1024 * 1024 + (1 << 17));   // 128 KB
  int* lst = (int*)(ws + (size_t)96 * 1024 * 1024 + (2 << 17));   //  8 MB
  _Float16* att16 = x16;  // x16 dead after GEMM1; total ws use ~104.5 MB

  // 1. x -> fp16
  k_cvt<<<dim3((B_ * T_ * C_) / 1024), dim3(256), 0, stream>>>(x, x16, B_ * T_ * C_);
  // 2. W_attn (2048 x 6144) -> WaT (6144 x 2048) fp16
  k_tconv<<<dim3(C3 / 32, C_ / 32), dim3(32, 8), 0, stream>>>(Wa, WaT, C_, C3);
  // 3. W_proj -> WpT fp16
  k_tconv<<<dim3(C_ / 32, C_ / 32), dim3(32, 8), 0, stream>>>(Wp, WpT, C_, C_);
  // 4. qkv = x @ W_attn + b_attn  (fp16 out)
  k_gemm<1><<<dim3(C3 / 128, (B_ * T_) / 128), dim3(256), 0, stream>>>(
      x16, WaT, ba, (void*)qkv16, B_ * T_, C3, C_);
  // 5. RoPE in place on q,k
  k_rope<<<dim3((B_ * T_ * 2048) / 256), dim3(256), 0, stream>>>(qkv16);
  // 6. death times (one wave per (h,j))
  k_death<<<dim3(H_ * T_ / 4), dim3(256), 0, stream>>>(rw, dd);
  // 7. key lists
  k_lists<<<dim3(H_ * T_), dim3(64), 0, stream>>>(dd, lst, cn);
  // 8. sparse attention -> att16 (B,T,C) fp16
  k_attn<<<dim3(B_ * H_ * T_), dim3(64), 0, stream>>>(qkv16, lst, cn, att16);
  // 9. out = att @ W_proj + b_proj (f32 out)
  k_gemm<0><<<dim3(C_ / 128, (B_ * T_) / 128), dim3(256), 0, stream>>>(
      att16, WpT, bp, d_out, B_ * T_, C_, C_);
}

// Round 3
// 471.340 us; speedup vs baseline: 1.6254x; 1.1014x over previous
//
#include <hip/hip_runtime.h>
#include <stdint.h>

#define B_ 2
#define T_ 2048
#define C_ 2048
#define H_ 16
#define D_ 128
#define KSP 64
#define C3 6144   // 3*C_

typedef __attribute__((ext_vector_type(4))) float f32x4;
typedef __attribute__((ext_vector_type(8))) _Float16 f16x8;
typedef __attribute__((ext_vector_type(4))) _Float16 f16x4;
typedef __attribute__((ext_vector_type(2))) _Float16 f16x2;

// global -> LDS async copy, 16B per lane. LDS dest is wave-uniform base + lane*16.
__device__ __forceinline__ void gload16(const void* g, void* l) {
  __builtin_amdgcn_global_load_lds(
      (__attribute__((address_space(1))) void*)(uintptr_t)g,
      (__attribute__((address_space(3))) void*)(uint32_t)(uintptr_t)l,
      16, 0, 0);
}

// ---------------- elementwise f32 -> f16 ----------------
__global__ void k_cvt(const float* __restrict__ in, _Float16* __restrict__ out, int n) {
  int i = (blockIdx.x * blockDim.x + threadIdx.x) * 4;
  if (i >= n) return;
  const float4 v = *(const float4*)(in + i);
  f16x4 o;
  o.x = (_Float16)v.x; o.y = (_Float16)v.y; o.z = (_Float16)v.z; o.w = (_Float16)v.w;
  *(f16x4*)(out + i) = o;
}

// ---------------- transpose + convert: W (K x N) f32 -> WT (N x K) f16 ----------------
__global__ void k_tconv(const float* __restrict__ W, _Float16* __restrict__ WT, int K, int N) {
  __shared__ float tile[32][33];
  const int n0 = blockIdx.x * 32, k0 = blockIdx.y * 32;
  const int tx = threadIdx.x, ty = threadIdx.y;  // 32 x 8
#pragma unroll
  for (int r = 0; r < 4; ++r)
    tile[ty + r * 8][tx] = W[(size_t)(k0 + ty + r * 8) * N + n0 + tx];
  __syncthreads();
#pragma unroll
  for (int r = 0; r < 4; ++r)
    WT[(size_t)(n0 + ty + r * 8) * K + k0 + tx] = (_Float16)tile[tx][ty + r * 8];
}

// ---------------- fp16 MFMA GEMM: C = A(MxK) * BT(NxK)^T + bias ----------------
// m97 structure: 128x128 tile, BK=32, 4 waves in 2x2 of 64x64, 16x16x32 MFMA.
template <int F16OUT>
__global__ __launch_bounds__(256) void k_gemm(const _Float16* __restrict__ A,
                                              const _Float16* __restrict__ BT,
                                              const float* __restrict__ bias,
                                              void* __restrict__ Cout,
                                              int M, int N, int K) {
  __shared__ __align__(16) _Float16 sA[128 * 32];
  __shared__ __align__(16) _Float16 sB[128 * 32];
  const int tid = threadIdx.x;
  const int lane = tid & 63;
  const int wid = tid >> 6;
  const int wr = wid >> 1, wc = wid & 1;
  const int bm = blockIdx.y, bn = blockIdx.x;
  const int lr = lane & 15;
  const int lk = (lane >> 4) << 3;
  f32x4 acc[4][4] = {};
  // staging: chunk id cid in [0,512): row = cid>>2, col8 = (cid&3)*8; flat f16 off = cid*8
  const int srow = tid >> 2, scol = (tid & 3) << 3;
  const _Float16* ag = A + (size_t)(bm * 128 + srow) * K + scol;
  const _Float16* bg = BT + (size_t)(bn * 128 + srow) * K + scol;
  _Float16* la = &sA[tid * 8];
  _Float16* lb = &sB[tid * 8];
  const int KH = 64 * K;  // +64 rows
  for (int k0 = 0; k0 < K; k0 += 32) {
    gload16(ag, la);
    gload16(ag + KH, la + 2048);
    gload16(bg, lb);
    gload16(bg + KH, lb + 2048);
    ag += 32; bg += 32;
    __syncthreads();  // drains vmcnt -> LDS tile ready
    f16x8 af[4], bf[4];
#pragma unroll
    for (int mi = 0; mi < 4; ++mi)
      af[mi] = *(const f16x8*)&sA[(wr * 64 + mi * 16 + lr) * 32 + lk];
#pragma unroll
    for (int nj = 0; nj < 4; ++nj)
      bf[nj] = *(const f16x8*)&sB[(wc * 64 + nj * 16 + lr) * 32 + lk];
#pragma unroll
    for (int mi = 0; mi < 4; ++mi)
#pragma unroll
      for (int nj = 0; nj < 4; ++nj)
        acc[mi][nj] = __builtin_amdgcn_mfma_f32_16x16x32_f16(af[mi], bf[nj], acc[mi][nj], 0, 0, 0);
    __syncthreads();  // all waves done with LDS before next overwrite
  }
  // C/D layout: row = (lane>>4)*4 + reg, col = lane&15
  const int row0 = bm * 128 + wr * 64;
  const int col0 = bn * 128 + wc * 64;
#pragma unroll
  for (int mi = 0; mi < 4; ++mi) {
#pragma unroll
    for (int nj = 0; nj < 4; ++nj) {
      const int col = col0 + nj * 16 + lr;
      const float bv = bias ? bias[col] : 0.f;
#pragma unroll
      for (int r = 0; r < 4; ++r) {
        const int row = row0 + mi * 16 + ((lane >> 4) << 2) + r;
        const float v = acc[mi][nj][r] + bv;
        if (F16OUT)
          ((_Float16*)Cout)[(size_t)row * N + col] = (_Float16)v;
        else
          ((float*)Cout)[(size_t)row * N + col] = v;
      }
    }
  }
}

// ---------------- in-place RoPE on q,k sections of qkv (B,T,3C) fp16 ----------------
__global__ void k_rope(_Float16* __restrict__ qkv) {
  const int idx = blockIdx.x * blockDim.x + threadIdx.x;  // exact grid
  const int pp = idx & 2047;   // pair slot within (b,t): [0,1024)=q, [1024,2048)=k
  const int bt = idx >> 11;
  const int t = bt & (T_ - 1);
  const int sec = pp >> 10;
  const int p = pp & 1023;
  const int hh = p >> 6;
  const int dp = p & 63;
  const float freq = expf(-0.14391156831212787f * (float)dp);  // 10000^(-dp/64)
  const float ang = (float)t * freq;
  float sn, cs;
  sincosf(ang, &sn, &cs);
  const size_t base = (size_t)bt * C3 + (size_t)sec * C_ + hh * D_ + 2 * dp;
  f16x2 v = *(f16x2*)(qkv + base);
  const float xe = (float)v.x, xo = (float)v.y;
  f16x2 o;
  o.x = (_Float16)(xe * cs - xo * sn);
  o.y = (_Float16)(xe * sn + xo * cs);
  *(f16x2*)(qkv + base) = o;
}

// ---------------- death time d[h][j]: index of 64th beater (T if <64 beaters) ----------------
// One WAVE per (h,j): ballot-based ordered count, <=32 wave-parallel steps.
__global__ __launch_bounds__(256) void k_death(const float* __restrict__ rw, int* __restrict__ dd) {
  const int widG = blockIdx.x * 4 + (threadIdx.x >> 6);  // global wave id = h*T_ + j
  const int lane = threadIdx.x & 63;
  const int h = widG >> 11, j = widG & (T_ - 1);
  const float* s = rw + h * T_;
  const float sj = s[j];
  int total = 0, d = T_;
  for (int base = 0; base < T_; base += 64) {
    const int t = base + lane;
    const float st = s[t];
    const bool beat = (st > sj) || (st == sj && t < j);
    const unsigned long long bal = __ballot(beat);
    const int c = __popcll(bal);
    if (total + c >= KSP) {  // wave-uniform condition
      const int need = KSP - total;  // 1-based rank within this chunk
      const int p = __popcll(bal & ((1ull << lane) - 1ull));
      const unsigned long long win = __ballot(beat && (p == need - 1));
      d = base + __builtin_ctzll(win);
      break;
    }
    total += c;
  }
  if (lane == 0) dd[widG] = d;
}

// ---------------- key lists: one wave per (h,i), ballot-compact {j<=i : d[h,j]>i} ----------------
__global__ __launch_bounds__(64) void k_lists(const int* __restrict__ dd,
                                              int* __restrict__ lst,
                                              int* __restrict__ cnt) {
  const int bid = blockIdx.x;  // h*T + i
  const int i = bid & (T_ - 1);
  const int h = bid >> 11;
  const int lane = threadIdx.x;
  const int* dh = dd + h * T_;
  int total = 0;
  for (int base = 0; base <= i; base += 64) {
    const int jx = base + lane;
    const bool pred = (jx <= i) && (dh[jx] > i);
    const unsigned long long bal = __ballot(pred);
    const int pos = total + __popcll(bal & ((1ull << lane) - 1ull));
    if (pred && pos < KSP) lst[(size_t)bid * KSP + pos] = jx;
    total += __popcll(bal);
  }
  if (lane == 0) cnt[bid] = total < KSP ? total : KSP;
}

// ---------------- sparse attention: one wave per (b,h,i) ----------------
// Phase 1: lane = key slot, packed-f16 dot via v_dot2_f32_f16 (4 acc chains).
// Phase 2: half-wave split (lanes 0-31: keys 0-31, lanes 32-63: keys 32-63),
//          each lane owns 4 dims, p+V-row-offset broadcast from LDS (1 ds_read_b64/iter),
//          final __shfl_xor(32) combine.
__global__ __launch_bounds__(64) void k_attn(const _Float16* __restrict__ qkv,
                                             const int* __restrict__ lst,
                                             const int* __restrict__ cnt,
                                             _Float16* __restrict__ out) {
  __shared__ uint2 spair[64];  // {bitcast(p), v-row element offset}
  const int bid = blockIdx.x;  // b*H*T + h*T + i
  const int i = bid & (T_ - 1);
  const int h = (bid >> 11) & (H_ - 1);
  const int b = bid >> 15;
  const int lane = threadIdx.x;
  const int c = cnt[(h << 11) + i];
  int j = 0;
  if (lane < c) j = lst[((size_t)((h << 11) + i)) * KSP + lane];
  // phase 1: lane = key slot; score = q . k_j / sqrt(D)
  const _Float16* qrow = qkv + (size_t)(b * T_ + i) * C3 + h * D_;
  const _Float16* krow = qkv + (size_t)(b * T_ + j) * C3 + C_ + h * D_;
  float a0 = 0.f, a1 = 0.f, a2 = 0.f, a3 = 0.f;
#if __has_builtin(__builtin_amdgcn_fdot2)
#pragma unroll
  for (int d8 = 0; d8 < D_ / 8; ++d8) {
    const f16x8 qv = ((const f16x8*)qrow)[d8];
    const f16x8 kv = ((const f16x8*)krow)[d8];
    const f16x2 q0 = __builtin_shufflevector(qv, qv, 0, 1);
    const f16x2 q1 = __builtin_shufflevector(qv, qv, 2, 3);
    const f16x2 q2 = __builtin_shufflevector(qv, qv, 4, 5);
    const f16x2 q3 = __builtin_shufflevector(qv, qv, 6, 7);
    const f16x2 k0 = __builtin_shufflevector(kv, kv, 0, 1);
    const f16x2 k1 = __builtin_shufflevector(kv, kv, 2, 3);
    const f16x2 k2 = __builtin_shufflevector(kv, kv, 4, 5);
    const f16x2 k3 = __builtin_shufflevector(kv, kv, 6, 7);
    a0 = __builtin_amdgcn_fdot2(q0, k0, a0, false);
    a1 = __builtin_amdgcn_fdot2(q1, k1, a1, false);
    a2 = __builtin_amdgcn_fdot2(q2, k2, a2, false);
    a3 = __builtin_amdgcn_fdot2(q3, k3, a3, false);
  }
#else
#pragma unroll
  for (int d8 = 0; d8 < D_ / 8; ++d8) {
    const f16x8 qv = ((const f16x8*)qrow)[d8];
    const f16x8 kv = ((const f16x8*)krow)[d8];
    a0 += (float)qv[0] * (float)kv[0] + (float)qv[1] * (float)kv[1];
    a1 += (float)qv[2] * (float)kv[2] + (float)qv[3] * (float)kv[3];
    a2 += (float)qv[4] * (float)kv[4] + (float)qv[5] * (float)kv[5];
    a3 += (float)qv[6] * (float)kv[6] + (float)qv[7] * (float)kv[7];
  }
#endif
  const float acc = (a0 + a1) + (a2 + a3);
  float score = (lane < c) ? acc * 0.08838834764831845f : -INFINITY;
  float m = score;
#pragma unroll
  for (int o = 32; o; o >>= 1) m = fmaxf(m, __shfl_xor(m, o));
  const float e = (lane < c) ? __expf(score - m) : 0.f;
  float ssum = e;
#pragma unroll
  for (int o = 32; o; o >>= 1) ssum += __shfl_xor(ssum, o);
  const float p = e / ssum;
  spair[lane] = make_uint2(__float_as_uint(p), (uint32_t)(j * C3));
  __syncthreads();
  // phase 2: half-wave over key slots, 4 dims per lane
  const int half = lane >> 5;
  const int dl = lane & 31;
  const int jbeg = half << 5;
  const int jend = (c < jbeg + 32) ? c : (jbeg + 32);
  const _Float16* vbase = qkv + (size_t)b * T_ * C3 + 2 * C_ + h * D_ + 4 * dl;
  float o0 = 0.f, o1 = 0.f, o2 = 0.f, o3 = 0.f;
  for (int jj = jbeg; jj < jend; ++jj) {
    const uint2 pr = spair[jj];
    const float pj = __uint_as_float(pr.x);
    const f16x4 vv = *(const f16x4*)(vbase + pr.y);
    o0 += pj * (float)vv.x;
    o1 += pj * (float)vv.y;
    o2 += pj * (float)vv.z;
    o3 += pj * (float)vv.w;
  }
  o0 += __shfl_xor(o0, 32);
  o1 += __shfl_xor(o1, 32);
  o2 += __shfl_xor(o2, 32);
  o3 += __shfl_xor(o3, 32);
  if (half == 0) {
    f16x4 ov;
    ov.x = (_Float16)o0;
    ov.y = (_Float16)o1;
    ov.z = (_Float16)o2;
    ov.w = (_Float16)o3;
    *(f16x4*)(out + (size_t)(b * T_ + i) * C_ + h * D_ + 4 * dl) = ov;
  }
}

extern "C" void kernel_launch(void* const* d_in, const int* in_sizes, int n_in,
                              void* d_out, int out_size, void* d_ws, size_t ws_size,
                              hipStream_t stream) {
  const float* x  = (const float*)d_in[0];
  const float* Wa = (const float*)d_in[1];
  const float* ba = (const float*)d_in[2];
  const float* Wp = (const float*)d_in[3];
  const float* bp = (const float*)d_in[4];
  const float* rw = (const float*)d_in[5];

  char* ws = (char*)d_ws;
  _Float16* qkv16 = (_Float16*)(ws);                              // 48 MB
  _Float16* WaT   = (_Float16*)(ws + (size_t)48 * 1024 * 1024);   // 24 MB
  _Float16* WpT   = (_Float16*)(ws + (size_t)72 * 1024 * 1024);   //  8 MB
  _Float16* x16   = (_Float16*)(ws + (size_t)80 * 1024 * 1024);   // 16 MB (reused as att16)
  int* dd  = (int*)(ws + (size_t)96 * 1024 * 1024);               // 128 KB
  int* cn  = (int*)(ws + (size_t)96 * 1024 * 1024 + (1 << 17));   // 128 KB
  int* lst = (int*)(ws + (size_t)96 * 1024 * 1024 + (2 << 17));   //  8 MB
  _Float16* att16 = x16;  // x16 dead after GEMM1; total ws use ~104.5 MB

  // 1. x -> fp16
  k_cvt<<<dim3((B_ * T_ * C_) / 1024), dim3(256), 0, stream>>>(x, x16, B_ * T_ * C_);
  // 2. W_attn (2048 x 6144) -> WaT (6144 x 2048) fp16
  k_tconv<<<dim3(C3 / 32, C_ / 32), dim3(32, 8), 0, stream>>>(Wa, WaT, C_, C3);
  // 3. W_proj -> WpT fp16
  k_tconv<<<dim3(C_ / 32, C_ / 32), dim3(32, 8), 0, stream>>>(Wp, WpT, C_, C_);
  // 4. qkv = x @ W_attn + b_attn  (fp16 out)
  k_gemm<1><<<dim3(C3 / 128, (B_ * T_) / 128), dim3(256), 0, stream>>>(
      x16, WaT, ba, (void*)qkv16, B_ * T_, C3, C_);
  // 5. RoPE in place on q,k
  k_rope<<<dim3((B_ * T_ * 2048) / 256), dim3(256), 0, stream>>>(qkv16);
  // 6. death times (one wave per (h,j))
  k_death<<<dim3(H_ * T_ / 4), dim3(256), 0, stream>>>(rw, dd);
  // 7. key lists
  k_lists<<<dim3(H_ * T_), dim3(64), 0, stream>>>(dd, lst, cn);
  // 8. sparse attention -> att16 (B,T,C) fp16
  k_attn<<<dim3(B_ * H_ * T_), dim3(64), 0, stream>>>(qkv16, lst, cn, att16);
  // 9. out = att @ W_proj + b_proj (f32 out)
  k_gemm<0><<<dim3(C_ / 128, (B_ * T_) / 128), dim3(256), 0, stream>>>(
      att16, WpT, bp, d_out, B_ * T_, C_, C_);
}

// Round 4
// 465.410 us; speedup vs baseline: 1.6461x; 1.0127x over previous
//
#include <hip/hip_runtime.h>
#include <stdint.h>

#define B_ 2
#define T_ 2048
#define C_ 2048
#define H_ 16
#define D_ 128
#define KSP 64
#define C3 6144   // 3*C_

typedef __attribute__((ext_vector_type(4))) float f32x4;
typedef __attribute__((ext_vector_type(8))) _Float16 f16x8;
typedef __attribute__((ext_vector_type(4))) _Float16 f16x4;
typedef __attribute__((ext_vector_type(2))) _Float16 f16x2;

// global -> LDS async copy, 16B per lane. LDS dest is wave-uniform base + lane*16.
__device__ __forceinline__ void gload16(const void* g, void* l) {
  __builtin_amdgcn_global_load_lds(
      (__attribute__((address_space(1))) void*)(uintptr_t)g,
      (__attribute__((address_space(3))) void*)(uint32_t)(uintptr_t)l,
      16, 0, 0);
}

// ---------------- elementwise f32 -> f16 ----------------
__global__ void k_cvt(const float* __restrict__ in, _Float16* __restrict__ out, int n) {
  int i = (blockIdx.x * blockDim.x + threadIdx.x) * 4;
  if (i >= n) return;
  const float4 v = *(const float4*)(in + i);
  f16x4 o;
  o.x = (_Float16)v.x; o.y = (_Float16)v.y; o.z = (_Float16)v.z; o.w = (_Float16)v.w;
  *(f16x4*)(out + i) = o;
}

// ---------------- transpose + convert: W (K x N) f32 -> WT (N x K) f16 ----------------
__global__ void k_tconv(const float* __restrict__ W, _Float16* __restrict__ WT, int K, int N) {
  __shared__ float tile[32][33];
  const int n0 = blockIdx.x * 32, k0 = blockIdx.y * 32;
  const int tx = threadIdx.x, ty = threadIdx.y;  // 32 x 8
#pragma unroll
  for (int r = 0; r < 4; ++r)
    tile[ty + r * 8][tx] = W[(size_t)(k0 + ty + r * 8) * N + n0 + tx];
  __syncthreads();
#pragma unroll
  for (int r = 0; r < 4; ++r)
    WT[(size_t)(n0 + ty + r * 8) * K + k0 + tx] = (_Float16)tile[tx][ty + r * 8];
}

// ---------------- fp16 MFMA GEMM: C = A(MxK) * BT(NxK)^T + bias ----------------
// m97 structure: 128x128 tile, BK=32, 4 waves in 2x2 of 64x64, 16x16x32 MFMA.
template <int F16OUT>
__global__ __launch_bounds__(256) void k_gemm(const _Float16* __restrict__ A,
                                              const _Float16* __restrict__ BT,
                                              const float* __restrict__ bias,
                                              void* __restrict__ Cout,
                                              int M, int N, int K) {
  __shared__ __align__(16) _Float16 sA[128 * 32];
  __shared__ __align__(16) _Float16 sB[128 * 32];
  const int tid = threadIdx.x;
  const int lane = tid & 63;
  const int wid = tid >> 6;
  const int wr = wid >> 1, wc = wid & 1;
  const int bm = blockIdx.y, bn = blockIdx.x;
  const int lr = lane & 15;
  const int lk = (lane >> 4) << 3;
  f32x4 acc[4][4] = {};
  // staging: chunk id cid in [0,512): row = cid>>2, col8 = (cid&3)*8; flat f16 off = cid*8
  const int srow = tid >> 2, scol = (tid & 3) << 3;
  const _Float16* ag = A + (size_t)(bm * 128 + srow) * K + scol;
  const _Float16* bg = BT + (size_t)(bn * 128 + srow) * K + scol;
  _Float16* la = &sA[tid * 8];
  _Float16* lb = &sB[tid * 8];
  const int KH = 64 * K;  // +64 rows
  for (int k0 = 0; k0 < K; k0 += 32) {
    gload16(ag, la);
    gload16(ag + KH, la + 2048);
    gload16(bg, lb);
    gload16(bg + KH, lb + 2048);
    ag += 32; bg += 32;
    __syncthreads();  // drains vmcnt -> LDS tile ready
    f16x8 af[4], bf[4];
#pragma unroll
    for (int mi = 0; mi < 4; ++mi)
      af[mi] = *(const f16x8*)&sA[(wr * 64 + mi * 16 + lr) * 32 + lk];
#pragma unroll
    for (int nj = 0; nj < 4; ++nj)
      bf[nj] = *(const f16x8*)&sB[(wc * 64 + nj * 16 + lr) * 32 + lk];
#pragma unroll
    for (int mi = 0; mi < 4; ++mi)
#pragma unroll
      for (int nj = 0; nj < 4; ++nj)
        acc[mi][nj] = __builtin_amdgcn_mfma_f32_16x16x32_f16(af[mi], bf[nj], acc[mi][nj], 0, 0, 0);
    __syncthreads();  // all waves done with LDS before next overwrite
  }
  // C/D layout: row = (lane>>4)*4 + reg, col = lane&15
  const int row0 = bm * 128 + wr * 64;
  const int col0 = bn * 128 + wc * 64;
#pragma unroll
  for (int mi = 0; mi < 4; ++mi) {
#pragma unroll
    for (int nj = 0; nj < 4; ++nj) {
      const int col = col0 + nj * 16 + lr;
      const float bv = bias ? bias[col] : 0.f;
#pragma unroll
      for (int r = 0; r < 4; ++r) {
        const int row = row0 + mi * 16 + ((lane >> 4) << 2) + r;
        const float v = acc[mi][nj][r] + bv;
        if (F16OUT)
          ((_Float16*)Cout)[(size_t)row * N + col] = (_Float16)v;
        else
          ((float*)Cout)[(size_t)row * N + col] = v;
      }
    }
  }
}

// ---------------- in-place RoPE on q,k sections of qkv (B,T,3C) fp16 ----------------
__global__ void k_rope(_Float16* __restrict__ qkv) {
  const int idx = blockIdx.x * blockDim.x + threadIdx.x;  // exact grid
  const int pp = idx & 2047;   // pair slot within (b,t): [0,1024)=q, [1024,2048)=k
  const int bt = idx >> 11;
  const int t = bt & (T_ - 1);
  const int sec = pp >> 10;
  const int p = pp & 1023;
  const int hh = p >> 6;
  const int dp = p & 63;
  const float freq = expf(-0.14391156831212787f * (float)dp);  // 10000^(-dp/64)
  const float ang = (float)t * freq;
  float sn, cs;
  sincosf(ang, &sn, &cs);
  const size_t base = (size_t)bt * C3 + (size_t)sec * C_ + hh * D_ + 2 * dp;
  f16x2 v = *(f16x2*)(qkv + base);
  const float xe = (float)v.x, xo = (float)v.y;
  f16x2 o;
  o.x = (_Float16)(xe * cs - xo * sn);
  o.y = (_Float16)(xe * sn + xo * cs);
  *(f16x2*)(qkv + base) = o;
}

// ---------------- death time d[h][j]: index of 64th beater (T if <64 beaters) ----------------
// One WAVE per (h,j): ballot-based ordered count, <=32 wave-parallel steps.
__global__ __launch_bounds__(256) void k_death(const float* __restrict__ rw, int* __restrict__ dd) {
  const int widG = blockIdx.x * 4 + (threadIdx.x >> 6);  // global wave id = h*T_ + j
  const int lane = threadIdx.x & 63;
  const int h = widG >> 11, j = widG & (T_ - 1);
  const float* s = rw + h * T_;
  const float sj = s[j];
  int total = 0, d = T_;
  for (int base = 0; base < T_; base += 64) {
    const int t = base + lane;
    const float st = s[t];
    const bool beat = (st > sj) || (st == sj && t < j);
    const unsigned long long bal = __ballot(beat);
    const int c = __popcll(bal);
    if (total + c >= KSP) {  // wave-uniform condition
      const int need = KSP - total;  // 1-based rank within this chunk
      const int p = __popcll(bal & ((1ull << lane) - 1ull));
      const unsigned long long win = __ballot(beat && (p == need - 1));
      d = base + __builtin_ctzll(win);
      break;
    }
    total += c;
  }
  if (lane == 0) dd[widG] = d;
}

// ---------------- key lists: one wave per (h,i), ballot-compact {j<=i : d[h,j]>i} ----------------
__global__ __launch_bounds__(64) void k_lists(const int* __restrict__ dd,
                                              int* __restrict__ lst,
                                              int* __restrict__ cnt) {
  const int bid = blockIdx.x;  // h*T + i
  const int i = bid & (T_ - 1);
  const int h = bid >> 11;
  const int lane = threadIdx.x;
  const int* dh = dd + h * T_;
  int total = 0;
  for (int base = 0; base <= i; base += 64) {
    const int jx = base + lane;
    const bool pred = (jx <= i) && (dh[jx] > i);
    const unsigned long long bal = __ballot(pred);
    const int pos = total + __popcll(bal & ((1ull << lane) - 1ull));
    if (pred && pos < KSP) lst[(size_t)bid * KSP + pos] = jx;
    total += __popcll(bal);
  }
  if (lane == 0) cnt[bid] = total < KSP ? total : KSP;
}

// ---------------- sparse attention: one wave per (b,h,i) ----------------
// Phase 1: lane = key slot, packed-f16 dot via v_dot2_f32_f16 (4 acc chains).
// Phase 2: half-wave split, FIXED 2x16 unrolled chunks (padding: p=0, j=0 -> valid
//          address, zero contribution) so 16 V-row loads are in flight at once
//          instead of one dependent ds_read->load->fma chain per key.
__global__ __launch_bounds__(64) void k_attn(const _Float16* __restrict__ qkv,
                                             const int* __restrict__ lst,
                                             const int* __restrict__ cnt,
                                             _Float16* __restrict__ out) {
  __shared__ uint2 spair[64];  // {bitcast(p), v-row element offset}
  const int bid = blockIdx.x;  // b*H*T + h*T + i
  const int i = bid & (T_ - 1);
  const int h = (bid >> 11) & (H_ - 1);
  const int b = bid >> 15;
  const int lane = threadIdx.x;
  const int c = cnt[(h << 11) + i];
  int j = 0;
  if (lane < c) j = lst[((size_t)((h << 11) + i)) * KSP + lane];
  // phase 1: lane = key slot; score = q . k_j / sqrt(D)
  const _Float16* qrow = qkv + (size_t)(b * T_ + i) * C3 + h * D_;
  const _Float16* krow = qkv + (size_t)(b * T_ + j) * C3 + C_ + h * D_;
  float a0 = 0.f, a1 = 0.f, a2 = 0.f, a3 = 0.f;
#if __has_builtin(__builtin_amdgcn_fdot2)
#pragma unroll
  for (int d8 = 0; d8 < D_ / 8; ++d8) {
    const f16x8 qv = ((const f16x8*)qrow)[d8];
    const f16x8 kv = ((const f16x8*)krow)[d8];
    const f16x2 q0 = __builtin_shufflevector(qv, qv, 0, 1);
    const f16x2 q1 = __builtin_shufflevector(qv, qv, 2, 3);
    const f16x2 q2 = __builtin_shufflevector(qv, qv, 4, 5);
    const f16x2 q3 = __builtin_shufflevector(qv, qv, 6, 7);
    const f16x2 k0 = __builtin_shufflevector(kv, kv, 0, 1);
    const f16x2 k1 = __builtin_shufflevector(kv, kv, 2, 3);
    const f16x2 k2 = __builtin_shufflevector(kv, kv, 4, 5);
    const f16x2 k3 = __builtin_shufflevector(kv, kv, 6, 7);
    a0 = __builtin_amdgcn_fdot2(q0, k0, a0, false);
    a1 = __builtin_amdgcn_fdot2(q1, k1, a1, false);
    a2 = __builtin_amdgcn_fdot2(q2, k2, a2, false);
    a3 = __builtin_amdgcn_fdot2(q3, k3, a3, false);
  }
#else
#pragma unroll
  for (int d8 = 0; d8 < D_ / 8; ++d8) {
    const f16x8 qv = ((const f16x8*)qrow)[d8];
    const f16x8 kv = ((const f16x8*)krow)[d8];
    a0 += (float)qv[0] * (float)kv[0] + (float)qv[1] * (float)kv[1];
    a1 += (float)qv[2] * (float)kv[2] + (float)qv[3] * (float)kv[3];
    a2 += (float)qv[4] * (float)kv[4] + (float)qv[5] * (float)kv[5];
    a3 += (float)qv[6] * (float)kv[6] + (float)qv[7] * (float)kv[7];
  }
#endif
  const float acc = (a0 + a1) + (a2 + a3);
  float score = (lane < c) ? acc * 0.08838834764831845f : -INFINITY;
  float m = score;
#pragma unroll
  for (int o = 32; o; o >>= 1) m = fmaxf(m, __shfl_xor(m, o));
  const float e = (lane < c) ? __expf(score - m) : 0.f;
  float ssum = e;
#pragma unroll
  for (int o = 32; o; o >>= 1) ssum += __shfl_xor(ssum, o);
  const float p = e / ssum;
  spair[lane] = make_uint2(__float_as_uint(p), (uint32_t)(j * C3));
  __syncthreads();  // workgroup == 1 wave: compiles to waitcnt only
  // phase 2: half-wave over key slots, 4 dims per lane, 2 chunks of 16.
  const int half = lane >> 5;
  const int dl = lane & 31;
  const int jbeg = half << 5;
  const _Float16* vbase = qkv + (size_t)b * T_ * C3 + 2 * C_ + h * D_ + 4 * dl;
  float o0 = 0.f, o1 = 0.f, o2 = 0.f, o3 = 0.f;
#pragma unroll
  for (int ch = 0; ch < 2; ++ch) {
    float pj[16];
    f16x4 vv[16];
#pragma unroll
    for (int u = 0; u < 16; ++u) {
      const uint2 pr = spair[jbeg + ch * 16 + u];
      pj[u] = __uint_as_float(pr.x);
      vv[u] = *(const f16x4*)(vbase + pr.y);
    }
#pragma unroll
    for (int u = 0; u < 16; ++u) {
      o0 += pj[u] * (float)vv[u].x;
      o1 += pj[u] * (float)vv[u].y;
      o2 += pj[u] * (float)vv[u].z;
      o3 += pj[u] * (float)vv[u].w;
    }
  }
  o0 += __shfl_xor(o0, 32);
  o1 += __shfl_xor(o1, 32);
  o2 += __shfl_xor(o2, 32);
  o3 += __shfl_xor(o3, 32);
  if (half == 0) {
    f16x4 ov;
    ov.x = (_Float16)o0;
    ov.y = (_Float16)o1;
    ov.z = (_Float16)o2;
    ov.w = (_Float16)o3;
    *(f16x4*)(out + (size_t)(b * T_ + i) * C_ + h * D_ + 4 * dl) = ov;
  }
}

extern "C" void kernel_launch(void* const* d_in, const int* in_sizes, int n_in,
                              void* d_out, int out_size, void* d_ws, size_t ws_size,
                              hipStream_t stream) {
  const float* x  = (const float*)d_in[0];
  const float* Wa = (const float*)d_in[1];
  const float* ba = (const float*)d_in[2];
  const float* Wp = (const float*)d_in[3];
  const float* bp = (const float*)d_in[4];
  const float* rw = (const float*)d_in[5];

  char* ws = (char*)d_ws;
  _Float16* qkv16 = (_Float16*)(ws);                              // 48 MB
  _Float16* WaT   = (_Float16*)(ws + (size_t)48 * 1024 * 1024);   // 24 MB
  _Float16* WpT   = (_Float16*)(ws + (size_t)72 * 1024 * 1024);   //  8 MB
  _Float16* x16   = (_Float16*)(ws + (size_t)80 * 1024 * 1024);   // 16 MB (reused as att16)
  int* dd  = (int*)(ws + (size_t)96 * 1024 * 1024);               // 128 KB
  int* cn  = (int*)(ws + (size_t)96 * 1024 * 1024 + (1 << 17));   // 128 KB
  int* lst = (int*)(ws + (size_t)96 * 1024 * 1024 + (2 << 17));   //  8 MB
  _Float16* att16 = x16;  // x16 dead after GEMM1; total ws use ~104.5 MB

  // 1. x -> fp16
  k_cvt<<<dim3((B_ * T_ * C_) / 1024), dim3(256), 0, stream>>>(x, x16, B_ * T_ * C_);
  // 2. W_attn (2048 x 6144) -> WaT (6144 x 2048) fp16
  k_tconv<<<dim3(C3 / 32, C_ / 32), dim3(32, 8), 0, stream>>>(Wa, WaT, C_, C3);
  // 3. W_proj -> WpT fp16
  k_tconv<<<dim3(C_ / 32, C_ / 32), dim3(32, 8), 0, stream>>>(Wp, WpT, C_, C_);
  // 4. qkv = x @ W_attn + b_attn  (fp16 out)
  k_gemm<1><<<dim3(C3 / 128, (B_ * T_) / 128), dim3(256), 0, stream>>>(
      x16, WaT, ba, (void*)qkv16, B_ * T_, C3, C_);
  // 5. RoPE in place on q,k
  k_rope<<<dim3((B_ * T_ * 2048) / 256), dim3(256), 0, stream>>>(qkv16);
  // 6. death times (one wave per (h,j))
  k_death<<<dim3(H_ * T_ / 4), dim3(256), 0, stream>>>(rw, dd);
  // 7. key lists
  k_lists<<<dim3(H_ * T_), dim3(64), 0, stream>>>(dd, lst, cn);
  // 8. sparse attention -> att16 (B,T,C) fp16
  k_attn<<<dim3(B_ * H_ * T_), dim3(64), 0, stream>>>(qkv16, lst, cn, att16);
  // 9. out = att @ W_proj + b_proj (f32 out)
  k_gemm<0><<<dim3(C_ / 128, (B_ * T_) / 128), dim3(256), 0, stream>>>(
      att16, WpT, bp, d_out, B_ * T_, C_, C_);
}

// Round 5
// 392.532 us; speedup vs baseline: 1.9518x; 1.1857x over previous
//
#include <hip/hip_runtime.h>
#include <stdint.h>

#define B_ 2
#define T_ 2048
#define C_ 2048
#define H_ 16
#define D_ 128
#define KSP 64
#define C3 6144   // 3*C_

typedef __attribute__((ext_vector_type(4))) float f32x4;
typedef __attribute__((ext_vector_type(8))) _Float16 f16x8;
typedef __attribute__((ext_vector_type(4))) _Float16 f16x4;
typedef __attribute__((ext_vector_type(2))) _Float16 f16x2;

// global -> LDS async copy, 16B per lane. LDS dest is wave-uniform base + lane*16.
__device__ __forceinline__ void gload16(const void* g, void* l) {
  __builtin_amdgcn_global_load_lds(
      (__attribute__((address_space(1))) void*)(uintptr_t)g,
      (__attribute__((address_space(3))) void*)(uint32_t)(uintptr_t)l,
      16, 0, 0);
}

// ---------------- elementwise f32 -> f16 ----------------
__global__ void k_cvt(const float* __restrict__ in, _Float16* __restrict__ out, int n) {
  int i = (blockIdx.x * blockDim.x + threadIdx.x) * 4;
  if (i >= n) return;
  const float4 v = *(const float4*)(in + i);
  f16x4 o;
  o.x = (_Float16)v.x; o.y = (_Float16)v.y; o.z = (_Float16)v.z; o.w = (_Float16)v.w;
  *(f16x4*)(out + i) = o;
}

// ---------------- transpose + convert: W (K x N) f32 -> WT (N x K) f16 ----------------
__global__ void k_tconv(const float* __restrict__ W, _Float16* __restrict__ WT, int K, int N) {
  __shared__ float tile[32][33];
  const int n0 = blockIdx.x * 32, k0 = blockIdx.y * 32;
  const int tx = threadIdx.x, ty = threadIdx.y;  // 32 x 8
#pragma unroll
  for (int r = 0; r < 4; ++r)
    tile[ty + r * 8][tx] = W[(size_t)(k0 + ty + r * 8) * N + n0 + tx];
  __syncthreads();
#pragma unroll
  for (int r = 0; r < 4; ++r)
    WT[(size_t)(n0 + ty + r * 8) * K + k0 + tx] = (_Float16)tile[tx][ty + r * 8];
}

// ---------------- fp16 MFMA GEMM: C = A(MxK) * BT(NxK)^T + bias ----------------
// m97 structure: 128x128 tile, BK=32, 4 waves in 2x2 of 64x64, 16x16x32 MFMA.
template <int F16OUT>
__global__ __launch_bounds__(256) void k_gemm(const _Float16* __restrict__ A,
                                              const _Float16* __restrict__ BT,
                                              const float* __restrict__ bias,
                                              void* __restrict__ Cout,
                                              int M, int N, int K) {
  __shared__ __align__(16) _Float16 sA[128 * 32];
  __shared__ __align__(16) _Float16 sB[128 * 32];
  const int tid = threadIdx.x;
  const int lane = tid & 63;
  const int wid = tid >> 6;
  const int wr = wid >> 1, wc = wid & 1;
  const int bm = blockIdx.y, bn = blockIdx.x;
  const int lr = lane & 15;
  const int lk = (lane >> 4) << 3;
  f32x4 acc[4][4] = {};
  // staging: chunk id cid in [0,512): row = cid>>2, col8 = (cid&3)*8; flat f16 off = cid*8
  const int srow = tid >> 2, scol = (tid & 3) << 3;
  const _Float16* ag = A + (size_t)(bm * 128 + srow) * K + scol;
  const _Float16* bg = BT + (size_t)(bn * 128 + srow) * K + scol;
  _Float16* la = &sA[tid * 8];
  _Float16* lb = &sB[tid * 8];
  const int KH = 64 * K;  // +64 rows
  for (int k0 = 0; k0 < K; k0 += 32) {
    gload16(ag, la);
    gload16(ag + KH, la + 2048);
    gload16(bg, lb);
    gload16(bg + KH, lb + 2048);
    ag += 32; bg += 32;
    __syncthreads();  // drains vmcnt -> LDS tile ready
    f16x8 af[4], bf[4];
#pragma unroll
    for (int mi = 0; mi < 4; ++mi)
      af[mi] = *(const f16x8*)&sA[(wr * 64 + mi * 16 + lr) * 32 + lk];
#pragma unroll
    for (int nj = 0; nj < 4; ++nj)
      bf[nj] = *(const f16x8*)&sB[(wc * 64 + nj * 16 + lr) * 32 + lk];
#pragma unroll
    for (int mi = 0; mi < 4; ++mi)
#pragma unroll
      for (int nj = 0; nj < 4; ++nj)
        acc[mi][nj] = __builtin_amdgcn_mfma_f32_16x16x32_f16(af[mi], bf[nj], acc[mi][nj], 0, 0, 0);
    __syncthreads();  // all waves done with LDS before next overwrite
  }
  // C/D layout: row = (lane>>4)*4 + reg, col = lane&15
  const int row0 = bm * 128 + wr * 64;
  const int col0 = bn * 128 + wc * 64;
#pragma unroll
  for (int mi = 0; mi < 4; ++mi) {
#pragma unroll
    for (int nj = 0; nj < 4; ++nj) {
      const int col = col0 + nj * 16 + lr;
      const float bv = bias ? bias[col] : 0.f;
#pragma unroll
      for (int r = 0; r < 4; ++r) {
        const int row = row0 + mi * 16 + ((lane >> 4) << 2) + r;
        const float v = acc[mi][nj][r] + bv;
        if (F16OUT)
          ((_Float16*)Cout)[(size_t)row * N + col] = (_Float16)v;
        else
          ((float*)Cout)[(size_t)row * N + col] = v;
      }
    }
  }
}

// ---------------- in-place RoPE on q,k sections of qkv (B,T,3C) fp16 ----------------
__global__ void k_rope(_Float16* __restrict__ qkv) {
  const int idx = blockIdx.x * blockDim.x + threadIdx.x;  // exact grid
  const int pp = idx & 2047;   // pair slot within (b,t): [0,1024)=q, [1024,2048)=k
  const int bt = idx >> 11;
  const int t = bt & (T_ - 1);
  const int sec = pp >> 10;
  const int p = pp & 1023;
  const int hh = p >> 6;
  const int dp = p & 63;
  const float freq = expf(-0.14391156831212787f * (float)dp);  // 10000^(-dp/64)
  const float ang = (float)t * freq;
  float sn, cs;
  sincosf(ang, &sn, &cs);
  const size_t base = (size_t)bt * C3 + (size_t)sec * C_ + hh * D_ + 2 * dp;
  f16x2 v = *(f16x2*)(qkv + base);
  const float xe = (float)v.x, xo = (float)v.y;
  f16x2 o;
  o.x = (_Float16)(xe * cs - xo * sn);
  o.y = (_Float16)(xe * sn + xo * cs);
  *(f16x2*)(qkv + base) = o;
}

// ---------------- death time d[h][j]: index of 64th beater (T if <64 beaters) ----------------
// One WAVE per (h,j): ballot-based ordered count, <=32 wave-parallel steps.
__global__ __launch_bounds__(256) void k_death(const float* __restrict__ rw, int* __restrict__ dd) {
  const int widG = blockIdx.x * 4 + (threadIdx.x >> 6);  // global wave id = h*T_ + j
  const int lane = threadIdx.x & 63;
  const int h = widG >> 11, j = widG & (T_ - 1);
  const float* s = rw + h * T_;
  const float sj = s[j];
  int total = 0, d = T_;
  for (int base = 0; base < T_; base += 64) {
    const int t = base + lane;
    const float st = s[t];
    const bool beat = (st > sj) || (st == sj && t < j);
    const unsigned long long bal = __ballot(beat);
    const int c = __popcll(bal);
    if (total + c >= KSP) {  // wave-uniform condition
      const int need = KSP - total;  // 1-based rank within this chunk
      const int p = __popcll(bal & ((1ull << lane) - 1ull));
      const unsigned long long win = __ballot(beat && (p == need - 1));
      d = base + __builtin_ctzll(win);
      break;
    }
    total += c;
  }
  if (lane == 0) dd[widG] = d;
}

// ---------------- key lists: one wave per (h,i), ballot-compact {j<=i : d[h,j]>i} ----------------
__global__ __launch_bounds__(64) void k_lists(const int* __restrict__ dd,
                                              int* __restrict__ lst,
                                              int* __restrict__ cnt) {
  const int bid = blockIdx.x;  // h*T + i
  const int i = bid & (T_ - 1);
  const int h = bid >> 11;
  const int lane = threadIdx.x;
  const int* dh = dd + h * T_;
  int total = 0;
  for (int base = 0; base <= i; base += 64) {
    const int jx = base + lane;
    const bool pred = (jx <= i) && (dh[jx] > i);
    const unsigned long long bal = __ballot(pred);
    const int pos = total + __popcll(bal & ((1ull << lane) - 1ull));
    if (pred && pos < KSP) lst[(size_t)bid * KSP + pos] = jx;
    total += __popcll(bal);
  }
  if (lane == 0) cnt[bid] = total < KSP ? total : KSP;
}

// ---------------- sparse attention: one wave per (b,h,i) ----------------
// Phase 1 (coalesced-transposed): lane = g*16+l (g: key subgroup 0..3, l: 8-dim chunk).
//   Step kb loads key j(kb*4+g): 16 lanes cover one 256B K-row contiguously, 4 rows/instr
//   (16 fully-used cachelines vs 64 sparse ones in the lane-per-key gather).
//   Partial dots reduce over l via shfl_xor(1,2,4,8); lane owns slot s=(l*4+g).
// Phase 2: half-wave split, 2x16 batched coalesced V loads (unchanged).
__global__ __launch_bounds__(64) void k_attn(const _Float16* __restrict__ qkv,
                                             const int* __restrict__ lst,
                                             const int* __restrict__ cnt,
                                             _Float16* __restrict__ out) {
  __shared__ uint2 spair[64];  // {bitcast(p), v-row element offset}
  const int bid = blockIdx.x;  // b*H*T + h*T + i
  const int i = bid & (T_ - 1);
  const int h = (bid >> 11) & (H_ - 1);
  const int b = bid >> 15;
  const int lane = threadIdx.x;
  const int g = lane >> 4;       // key subgroup
  const int l = lane & 15;       // dim chunk
  const int c = cnt[(h << 11) + i];
  const int* mylst = lst + ((size_t)((h << 11) + i)) * KSP;
  // owned slot: s_own = l*4 + g  (bijection over 64 slots)
  const int s_own = l * 4 + g;
  const int j_own = (s_own < c) ? mylst[s_own] : 0;
  // q chunk for this lane's dim group (broadcast across g)
  const _Float16* qkvb = qkv + (size_t)b * T_ * C3;
  const f16x8 qv = *(const f16x8*)(qkvb + (size_t)i * C3 + h * D_ + l * 8);
  const f16x2 q0 = __builtin_shufflevector(qv, qv, 0, 1);
  const f16x2 q1 = __builtin_shufflevector(qv, qv, 2, 3);
  const f16x2 q2 = __builtin_shufflevector(qv, qv, 4, 5);
  const f16x2 q3 = __builtin_shufflevector(qv, qv, 6, 7);
  const _Float16* kbase = qkvb + C_ + h * D_ + l * 8;
  float p[16];
#pragma unroll
  for (int hf = 0; hf < 2; ++hf) {
    f16x8 vk[8];
#pragma unroll
    for (int u = 0; u < 8; ++u) {
      const int kb = hf * 8 + u;
      const int jk = __shfl(j_own, (lane & 48) + kb);  // owner lane of slot kb*4+g
      vk[u] = *(const f16x8*)(kbase + (size_t)jk * C3);
    }
#pragma unroll
    for (int u = 0; u < 8; ++u) {
      float a0 = 0.f, a1 = 0.f;
#if __has_builtin(__builtin_amdgcn_fdot2)
      a0 = __builtin_amdgcn_fdot2(q0, __builtin_shufflevector(vk[u], vk[u], 0, 1), a0, false);
      a1 = __builtin_amdgcn_fdot2(q1, __builtin_shufflevector(vk[u], vk[u], 2, 3), a1, false);
      a0 = __builtin_amdgcn_fdot2(q2, __builtin_shufflevector(vk[u], vk[u], 4, 5), a0, false);
      a1 = __builtin_amdgcn_fdot2(q3, __builtin_shufflevector(vk[u], vk[u], 6, 7), a1, false);
#else
#pragma unroll
      for (int t = 0; t < 8; t += 2) {
        a0 += (float)qv[t] * (float)vk[u][t];
        a1 += (float)qv[t + 1] * (float)vk[u][t + 1];
      }
#endif
      p[hf * 8 + u] = a0 + a1;
    }
  }
  // reduce over dim-chunks (lanes with same g), mask invalid slots, scale
#pragma unroll
  for (int kb = 0; kb < 16; ++kb) {
    float t = p[kb];
    t += __shfl_xor(t, 1);
    t += __shfl_xor(t, 2);
    t += __shfl_xor(t, 4);
    t += __shfl_xor(t, 8);
    p[kb] = (kb * 4 + g < c) ? t * 0.08838834764831845f : -INFINITY;
  }
  // wave max
  float m = p[0];
#pragma unroll
  for (int kb = 1; kb < 16; ++kb) m = fmaxf(m, p[kb]);
  m = fmaxf(m, __shfl_xor(m, 16));
  m = fmaxf(m, __shfl_xor(m, 32));
  // wave sum of exps
  float ssum = 0.f;
#pragma unroll
  for (int kb = 0; kb < 16; ++kb) ssum += __expf(p[kb] - m);
  ssum += __shfl_xor(ssum, 16);
  ssum += __shfl_xor(ssum, 32);
  // select own slot's score (compile-time-indexed cndmask chain)
  float pown = p[0];
#pragma unroll
  for (int kb = 1; kb < 16; ++kb) pown = (l == kb) ? p[kb] : pown;
  const float pfin = __expf(pown - m) / ssum;
  spair[s_own] = make_uint2(__float_as_uint(pfin), (uint32_t)(j_own * C3));
  __syncthreads();  // single-wave block: compiles to waitcnt
  // phase 2: half-wave over key slots, 4 dims per lane, 2 chunks of 16.
  const int half = lane >> 5;
  const int dl = lane & 31;
  const int jbeg = half << 5;
  const _Float16* vbase = qkvb + 2 * C_ + h * D_ + 4 * dl;
  float o0 = 0.f, o1 = 0.f, o2 = 0.f, o3 = 0.f;
#pragma unroll
  for (int ch = 0; ch < 2; ++ch) {
    float pj[16];
    f16x4 vv[16];
#pragma unroll
    for (int u = 0; u < 16; ++u) {
      const uint2 pr = spair[jbeg + ch * 16 + u];
      pj[u] = __uint_as_float(pr.x);
      vv[u] = *(const f16x4*)(vbase + pr.y);
    }
#pragma unroll
    for (int u = 0; u < 16; ++u) {
      o0 += pj[u] * (float)vv[u].x;
      o1 += pj[u] * (float)vv[u].y;
      o2 += pj[u] * (float)vv[u].z;
      o3 += pj[u] * (float)vv[u].w;
    }
  }
  o0 += __shfl_xor(o0, 32);
  o1 += __shfl_xor(o1, 32);
  o2 += __shfl_xor(o2, 32);
  o3 += __shfl_xor(o3, 32);
  if (half == 0) {
    f16x4 ov;
    ov.x = (_Float16)o0;
    ov.y = (_Float16)o1;
    ov.z = (_Float16)o2;
    ov.w = (_Float16)o3;
    *(f16x4*)(out + (size_t)(b * T_ + i) * C_ + h * D_ + 4 * dl) = ov;
  }
}

extern "C" void kernel_launch(void* const* d_in, const int* in_sizes, int n_in,
                              void* d_out, int out_size, void* d_ws, size_t ws_size,
                              hipStream_t stream) {
  const float* x  = (const float*)d_in[0];
  const float* Wa = (const float*)d_in[1];
  const float* ba = (const float*)d_in[2];
  const float* Wp = (const float*)d_in[3];
  const float* bp = (const float*)d_in[4];
  const float* rw = (const float*)d_in[5];

  char* ws = (char*)d_ws;
  _Float16* qkv16 = (_Float16*)(ws);                              // 48 MB
  _Float16* WaT   = (_Float16*)(ws + (size_t)48 * 1024 * 1024);   // 24 MB
  _Float16* WpT   = (_Float16*)(ws + (size_t)72 * 1024 * 1024);   //  8 MB
  _Float16* x16   = (_Float16*)(ws + (size_t)80 * 1024 * 1024);   // 16 MB (reused as att16)
  int* dd  = (int*)(ws + (size_t)96 * 1024 * 1024);               // 128 KB
  int* cn  = (int*)(ws + (size_t)96 * 1024 * 1024 + (1 << 17));   // 128 KB
  int* lst = (int*)(ws + (size_t)96 * 1024 * 1024 + (2 << 17));   //  8 MB
  _Float16* att16 = x16;  // x16 dead after GEMM1; total ws use ~104.5 MB

  // 1. x -> fp16
  k_cvt<<<dim3((B_ * T_ * C_) / 1024), dim3(256), 0, stream>>>(x, x16, B_ * T_ * C_);
  // 2. W_attn (2048 x 6144) -> WaT (6144 x 2048) fp16
  k_tconv<<<dim3(C3 / 32, C_ / 32), dim3(32, 8), 0, stream>>>(Wa, WaT, C_, C3);
  // 3. W_proj -> WpT fp16
  k_tconv<<<dim3(C_ / 32, C_ / 32), dim3(32, 8), 0, stream>>>(Wp, WpT, C_, C_);
  // 4. qkv = x @ W_attn + b_attn  (fp16 out)
  k_gemm<1><<<dim3(C3 / 128, (B_ * T_) / 128), dim3(256), 0, stream>>>(
      x16, WaT, ba, (void*)qkv16, B_ * T_, C3, C_);
  // 5. RoPE in place on q,k
  k_rope<<<dim3((B_ * T_ * 2048) / 256), dim3(256), 0, stream>>>(qkv16);
  // 6. death times (one wave per (h,j))
  k_death<<<dim3(H_ * T_ / 4), dim3(256), 0, stream>>>(rw, dd);
  // 7. key lists
  k_lists<<<dim3(H_ * T_), dim3(64), 0, stream>>>(dd, lst, cn);
  // 8. sparse attention -> att16 (B,T,C) fp16
  k_attn<<<dim3(B_ * H_ * T_), dim3(64), 0, stream>>>(qkv16, lst, cn, att16);
  // 9. out = att @ W_proj + b_proj (f32 out)
  k_gemm<0><<<dim3(C_ / 128, (B_ * T_) / 128), dim3(256), 0, stream>>>(
      att16, WpT, bp, d_out, B_ * T_, C_, C_);
}

// Round 6
// 372.959 us; speedup vs baseline: 2.0542x; 1.0525x over previous
//
#include <hip/hip_runtime.h>
#include <stdint.h>

#define B_ 2
#define T_ 2048
#define C_ 2048
#define H_ 16
#define D_ 128
#define KSP 64
#define C3 6144   // 3*C_

typedef __attribute__((ext_vector_type(4))) float f32x4;
typedef __attribute__((ext_vector_type(8))) _Float16 f16x8;
typedef __attribute__((ext_vector_type(4))) _Float16 f16x4;
typedef __attribute__((ext_vector_type(2))) _Float16 f16x2;

// global -> LDS async copy, 16B per lane. LDS dest is wave-uniform base + lane*16.
__device__ __forceinline__ void gload16(const void* g, void* l) {
  __builtin_amdgcn_global_load_lds(
      (__attribute__((address_space(1))) void*)(uintptr_t)g,
      (__attribute__((address_space(3))) void*)(uint32_t)(uintptr_t)l,
      16, 0, 0);
}

// ---------------- elementwise f32 -> f16 ----------------
__global__ void k_cvt(const float* __restrict__ in, _Float16* __restrict__ out, int n) {
  int i = (blockIdx.x * blockDim.x + threadIdx.x) * 4;
  if (i >= n) return;
  const float4 v = *(const float4*)(in + i);
  f16x4 o;
  o.x = (_Float16)v.x; o.y = (_Float16)v.y; o.z = (_Float16)v.z; o.w = (_Float16)v.w;
  *(f16x4*)(out + i) = o;
}

// ---------------- transpose + convert: W (K x N) f32 -> WT (N x K) f16 ----------------
__global__ void k_tconv(const float* __restrict__ W, _Float16* __restrict__ WT, int K, int N) {
  __shared__ float tile[32][33];
  const int n0 = blockIdx.x * 32, k0 = blockIdx.y * 32;
  const int tx = threadIdx.x, ty = threadIdx.y;  // 32 x 8
#pragma unroll
  for (int r = 0; r < 4; ++r)
    tile[ty + r * 8][tx] = W[(size_t)(k0 + ty + r * 8) * N + n0 + tx];
  __syncthreads();
#pragma unroll
  for (int r = 0; r < 4; ++r)
    WT[(size_t)(n0 + ty + r * 8) * K + k0 + tx] = (_Float16)tile[tx][ty + r * 8];
}

// ---------------- fp16 MFMA GEMM, deep-pipelined: C = A(MxK) * BT(NxK)^T + bias ----------------
// BM=256, BK=32, 8 waves (2 M x 4 N). NJ = 16-col fragments per wave => BN = 64*NJ.
// T4: counted vmcnt across raw s_barriers (no vmcnt(0) drain in main loop).
// T2: granule rotation (gr + row/2)&3 -> each 8 consecutive lanes of a ds_read_b128
//     cover all 32 banks. global_load_lds dest stays LINEAR (lane-ordered); the
//     global SOURCE is inverse-rotated, the LDS READ is rotated (both-sides rule).
// T1: XCD-bijective block swizzle (grid % 8 == 0 for both call sites).
template <int F16OUT, int NJ>
__global__ __launch_bounds__(512) void k_gemm256(const _Float16* __restrict__ A,
                                                 const _Float16* __restrict__ BT,
                                                 const float* __restrict__ bias,
                                                 void* __restrict__ Cout,
                                                 int M, int N, int K,
                                                 int nbm, int nbn) {
  constexpr int BN = 64 * NJ;
  constexpr int LPT = 2 + (NJ >> 1);  // gload16 per thread per K-tile (A:2 rounds, B:NJ/2)
  __shared__ __align__(16) _Float16 sA[2][256 * 32];
  __shared__ __align__(16) _Float16 sB[2][BN * 32];
  const int tid = threadIdx.x;
  const int lane = tid & 63;
  const int wid = tid >> 6;
  const int wr = wid >> 2;   // 0..1  (M half)
  const int wc = wid & 3;    // 0..3  (N quarter)
  const int lr = lane & 15;
  const int g = lane >> 4;   // k-granule 0..3 (16B granules of the 64B k-row)
  // XCD-bijective swizzle (nwg % 8 == 0 at both call sites)
  const int nwg = nbm * nbn;
  const int bid = blockIdx.x;
  const int swz = (bid & 7) * (nwg >> 3) + (bid >> 3);
  const int bm = swz / nbn, bn = swz % nbn;
  const size_t arow0 = (size_t)bm * 256;
  const size_t brow0 = (size_t)bn * BN;

  f32x4 acc[8][NJ];
#pragma unroll
  for (int mi = 0; mi < 8; ++mi)
#pragma unroll
    for (int nj = 0; nj < NJ; ++nj) acc[mi][nj] = (f32x4){0.f, 0.f, 0.f, 0.f};

  auto STAGE = [&](int slot, int k0) {
#pragma unroll
    for (int r = 0; r < 2; ++r) {
      const int u = tid + r * 512;          // granule id; per-wave lane-ordered => linear dest ok
      const int row = u >> 2, grl = u & 3;
      const int grn = (grl - (row >> 1)) & 3;  // inverse rotation on the SOURCE
      gload16(A + (arow0 + row) * K + k0 + grn * 8, &sA[slot][u * 8]);
    }
#pragma unroll
    for (int r = 0; r < NJ / 2; ++r) {
      const int u = tid + r * 512;
      const int row = u >> 2, grl = u & 3;
      const int grn = (grl - (row >> 1)) & 3;
      gload16(BT + (brow0 + row) * K + k0 + grn * 8, &sB[slot][u * 8]);
    }
  };

  const int NT = K >> 5;
  STAGE(0, 0);
  STAGE(1, 32);
  for (int t = 0; t < NT; ++t) {
    const int s = t & 1;
    if (t == NT - 1)
      asm volatile("s_waitcnt vmcnt(0)" ::: "memory");
    else
      asm volatile("s_waitcnt vmcnt(%0)" ::"i"(LPT) : "memory");  // tile t landed; t+1 in flight
    __builtin_amdgcn_s_barrier();
    __builtin_amdgcn_sched_barrier(0);
    f16x8 af[8], bf[NJ];
#pragma unroll
    for (int mi = 0; mi < 8; ++mi) {
      const int row = wr * 128 + mi * 16 + lr;
      af[mi] = *(const f16x8*)&sA[s][row * 32 + (((g + (row >> 1)) & 3) << 3)];
    }
#pragma unroll
    for (int nj = 0; nj < NJ; ++nj) {
      const int row = wc * (16 * NJ) + nj * 16 + lr;
      bf[nj] = *(const f16x8*)&sB[s][row * 32 + (((g + (row >> 1)) & 3) << 3)];
    }
#pragma unroll
    for (int mi = 0; mi < 8; ++mi)
#pragma unroll
      for (int nj = 0; nj < NJ; ++nj)
        acc[mi][nj] = __builtin_amdgcn_mfma_f32_16x16x32_f16(af[mi], bf[nj], acc[mi][nj], 0, 0, 0);
    __builtin_amdgcn_sched_barrier(0);
    __builtin_amdgcn_s_barrier();
    __builtin_amdgcn_sched_barrier(0);
    if (t + 2 < NT) STAGE(s, (t + 2) * 32);  // overwrite slot s: all reads of it are done
  }
  // epilogue: C/D layout row = g*4 + r, col = lr (per 16x16 fragment)
  const size_t row0 = arow0 + wr * 128;
  const size_t col0 = brow0 + wc * (16 * NJ);
#pragma unroll
  for (int mi = 0; mi < 8; ++mi) {
#pragma unroll
    for (int nj = 0; nj < NJ; ++nj) {
      const size_t col = col0 + nj * 16 + lr;
      const float bv = bias[col];
#pragma unroll
      for (int r = 0; r < 4; ++r) {
        const size_t row = row0 + mi * 16 + g * 4 + r;
        const float v = acc[mi][nj][r] + bv;
        if (F16OUT)
          ((_Float16*)Cout)[row * N + col] = (_Float16)v;
        else
          ((float*)Cout)[row * N + col] = v;
      }
    }
  }
}

// ---------------- in-place RoPE on q,k sections of qkv (B,T,3C) fp16 ----------------
__global__ void k_rope(_Float16* __restrict__ qkv) {
  const int idx = blockIdx.x * blockDim.x + threadIdx.x;  // exact grid
  const int pp = idx & 2047;   // pair slot within (b,t): [0,1024)=q, [1024,2048)=k
  const int bt = idx >> 11;
  const int t = bt & (T_ - 1);
  const int sec = pp >> 10;
  const int p = pp & 1023;
  const int hh = p >> 6;
  const int dp = p & 63;
  const float freq = expf(-0.14391156831212787f * (float)dp);  // 10000^(-dp/64)
  const float ang = (float)t * freq;
  float sn, cs;
  sincosf(ang, &sn, &cs);
  const size_t base = (size_t)bt * C3 + (size_t)sec * C_ + hh * D_ + 2 * dp;
  f16x2 v = *(f16x2*)(qkv + base);
  const float xe = (float)v.x, xo = (float)v.y;
  f16x2 o;
  o.x = (_Float16)(xe * cs - xo * sn);
  o.y = (_Float16)(xe * sn + xo * cs);
  *(f16x2*)(qkv + base) = o;
}

// ---------------- death time d[h][j]: index of 64th beater (T if <64 beaters) ----------------
// One WAVE per (h,j): ballot-based ordered count, <=32 wave-parallel steps.
__global__ __launch_bounds__(256) void k_death(const float* __restrict__ rw, int* __restrict__ dd) {
  const int widG = blockIdx.x * 4 + (threadIdx.x >> 6);  // global wave id = h*T_ + j
  const int lane = threadIdx.x & 63;
  const int h = widG >> 11, j = widG & (T_ - 1);
  const float* s = rw + h * T_;
  const float sj = s[j];
  int total = 0, d = T_;
  for (int base = 0; base < T_; base += 64) {
    const int t = base + lane;
    const float st = s[t];
    const bool beat = (st > sj) || (st == sj && t < j);
    const unsigned long long bal = __ballot(beat);
    const int c = __popcll(bal);
    if (total + c >= KSP) {  // wave-uniform condition
      const int need = KSP - total;  // 1-based rank within this chunk
      const int p = __popcll(bal & ((1ull << lane) - 1ull));
      const unsigned long long win = __ballot(beat && (p == need - 1));
      d = base + __builtin_ctzll(win);
      break;
    }
    total += c;
  }
  if (lane == 0) dd[widG] = d;
}

// ---------------- key lists: one wave per (h,i), ballot-compact {j<=i : d[h,j]>i} ----------------
__global__ __launch_bounds__(64) void k_lists(const int* __restrict__ dd,
                                              int* __restrict__ lst,
                                              int* __restrict__ cnt) {
  const int bid = blockIdx.x;  // h*T + i
  const int i = bid & (T_ - 1);
  const int h = bid >> 11;
  const int lane = threadIdx.x;
  const int* dh = dd + h * T_;
  int total = 0;
  for (int base = 0; base <= i; base += 64) {
    const int jx = base + lane;
    const bool pred = (jx <= i) && (dh[jx] > i);
    const unsigned long long bal = __ballot(pred);
    const int pos = total + __popcll(bal & ((1ull << lane) - 1ull));
    if (pred && pos < KSP) lst[(size_t)bid * KSP + pos] = jx;
    total += __popcll(bal);
  }
  if (lane == 0) cnt[bid] = total < KSP ? total : KSP;
}

// ---------------- sparse attention: one wave per (b,h,i) ----------------
// Phase 1 (coalesced-transposed): lane = g*16+l (g: key subgroup 0..3, l: 8-dim chunk).
// Phase 2: half-wave split, 2x16 batched coalesced V loads.
__global__ __launch_bounds__(64) void k_attn(const _Float16* __restrict__ qkv,
                                             const int* __restrict__ lst,
                                             const int* __restrict__ cnt,
                                             _Float16* __restrict__ out) {
  __shared__ uint2 spair[64];  // {bitcast(p), v-row element offset}
  const int bid = blockIdx.x;  // b*H*T + h*T + i
  const int i = bid & (T_ - 1);
  const int h = (bid >> 11) & (H_ - 1);
  const int b = bid >> 15;
  const int lane = threadIdx.x;
  const int g = lane >> 4;       // key subgroup
  const int l = lane & 15;       // dim chunk
  const int c = cnt[(h << 11) + i];
  const int* mylst = lst + ((size_t)((h << 11) + i)) * KSP;
  // owned slot: s_own = l*4 + g  (bijection over 64 slots)
  const int s_own = l * 4 + g;
  const int j_own = (s_own < c) ? mylst[s_own] : 0;
  // q chunk for this lane's dim group (broadcast across g)
  const _Float16* qkvb = qkv + (size_t)b * T_ * C3;
  const f16x8 qv = *(const f16x8*)(qkvb + (size_t)i * C3 + h * D_ + l * 8);
  const f16x2 q0 = __builtin_shufflevector(qv, qv, 0, 1);
  const f16x2 q1 = __builtin_shufflevector(qv, qv, 2, 3);
  const f16x2 q2 = __builtin_shufflevector(qv, qv, 4, 5);
  const f16x2 q3 = __builtin_shufflevector(qv, qv, 6, 7);
  const _Float16* kbase = qkvb + C_ + h * D_ + l * 8;
  float p[16];
#pragma unroll
  for (int hf = 0; hf < 2; ++hf) {
    f16x8 vk[8];
#pragma unroll
    for (int u = 0; u < 8; ++u) {
      const int kb = hf * 8 + u;
      const int jk = __shfl(j_own, (lane & 48) + kb);  // owner lane of slot kb*4+g
      vk[u] = *(const f16x8*)(kbase + (size_t)jk * C3);
    }
#pragma unroll
    for (int u = 0; u < 8; ++u) {
      float a0 = 0.f, a1 = 0.f;
#if __has_builtin(__builtin_amdgcn_fdot2)
      a0 = __builtin_amdgcn_fdot2(q0, __builtin_shufflevector(vk[u], vk[u], 0, 1), a0, false);
      a1 = __builtin_amdgcn_fdot2(q1, __builtin_shufflevector(vk[u], vk[u], 2, 3), a1, false);
      a0 = __builtin_amdgcn_fdot2(q2, __builtin_shufflevector(vk[u], vk[u], 4, 5), a0, false);
      a1 = __builtin_amdgcn_fdot2(q3, __builtin_shufflevector(vk[u], vk[u], 6, 7), a1, false);
#else
#pragma unroll
      for (int t = 0; t < 8; t += 2) {
        a0 += (float)qv[t] * (float)vk[u][t];
        a1 += (float)qv[t + 1] * (float)vk[u][t + 1];
      }
#endif
      p[hf * 8 + u] = a0 + a1;
    }
  }
  // reduce over dim-chunks (lanes with same g), mask invalid slots, scale
#pragma unroll
  for (int kb = 0; kb < 16; ++kb) {
    float t = p[kb];
    t += __shfl_xor(t, 1);
    t += __shfl_xor(t, 2);
    t += __shfl_xor(t, 4);
    t += __shfl_xor(t, 8);
    p[kb] = (kb * 4 + g < c) ? t * 0.08838834764831845f : -INFINITY;
  }
  // wave max
  float m = p[0];
#pragma unroll
  for (int kb = 1; kb < 16; ++kb) m = fmaxf(m, p[kb]);
  m = fmaxf(m, __shfl_xor(m, 16));
  m = fmaxf(m, __shfl_xor(m, 32));
  // wave sum of exps
  float ssum = 0.f;
#pragma unroll
  for (int kb = 0; kb < 16; ++kb) ssum += __expf(p[kb] - m);
  ssum += __shfl_xor(ssum, 16);
  ssum += __shfl_xor(ssum, 32);
  // select own slot's score (compile-time-indexed cndmask chain)
  float pown = p[0];
#pragma unroll
  for (int kb = 1; kb < 16; ++kb) pown = (l == kb) ? p[kb] : pown;
  const float pfin = __expf(pown - m) / ssum;
  spair[s_own] = make_uint2(__float_as_uint(pfin), (uint32_t)(j_own * C3));
  __syncthreads();  // single-wave block: compiles to waitcnt
  // phase 2: half-wave over key slots, 4 dims per lane, 2 chunks of 16.
  const int half = lane >> 5;
  const int dl = lane & 31;
  const int jbeg = half << 5;
  const _Float16* vbase = qkvb + 2 * C_ + h * D_ + 4 * dl;
  float o0 = 0.f, o1 = 0.f, o2 = 0.f, o3 = 0.f;
#pragma unroll
  for (int ch = 0; ch < 2; ++ch) {
    float pj[16];
    f16x4 vv[16];
#pragma unroll
    for (int u = 0; u < 16; ++u) {
      const uint2 pr = spair[jbeg + ch * 16 + u];
      pj[u] = __uint_as_float(pr.x);
      vv[u] = *(const f16x4*)(vbase + pr.y);
    }
#pragma unroll
    for (int u = 0; u < 16; ++u) {
      o0 += pj[u] * (float)vv[u].x;
      o1 += pj[u] * (float)vv[u].y;
      o2 += pj[u] * (float)vv[u].z;
      o3 += pj[u] * (float)vv[u].w;
    }
  }
  o0 += __shfl_xor(o0, 32);
  o1 += __shfl_xor(o1, 32);
  o2 += __shfl_xor(o2, 32);
  o3 += __shfl_xor(o3, 32);
  if (half == 0) {
    f16x4 ov;
    ov.x = (_Float16)o0;
    ov.y = (_Float16)o1;
    ov.z = (_Float16)o2;
    ov.w = (_Float16)o3;
    *(f16x4*)(out + (size_t)(b * T_ + i) * C_ + h * D_ + 4 * dl) = ov;
  }
}

extern "C" void kernel_launch(void* const* d_in, const int* in_sizes, int n_in,
                              void* d_out, int out_size, void* d_ws, size_t ws_size,
                              hipStream_t stream) {
  const float* x  = (const float*)d_in[0];
  const float* Wa = (const float*)d_in[1];
  const float* ba = (const float*)d_in[2];
  const float* Wp = (const float*)d_in[3];
  const float* bp = (const float*)d_in[4];
  const float* rw = (const float*)d_in[5];

  char* ws = (char*)d_ws;
  _Float16* qkv16 = (_Float16*)(ws);                              // 48 MB
  _Float16* WaT   = (_Float16*)(ws + (size_t)48 * 1024 * 1024);   // 24 MB
  _Float16* WpT   = (_Float16*)(ws + (size_t)72 * 1024 * 1024);   //  8 MB
  _Float16* x16   = (_Float16*)(ws + (size_t)80 * 1024 * 1024);   // 16 MB (reused as att16)
  int* dd  = (int*)(ws + (size_t)96 * 1024 * 1024);               // 128 KB
  int* cn  = (int*)(ws + (size_t)96 * 1024 * 1024 + (1 << 17));   // 128 KB
  int* lst = (int*)(ws + (size_t)96 * 1024 * 1024 + (2 << 17));   //  8 MB
  _Float16* att16 = x16;  // x16 dead after GEMM1; total ws use ~104.5 MB

  // 1. x -> fp16
  k_cvt<<<dim3((B_ * T_ * C_) / 1024), dim3(256), 0, stream>>>(x, x16, B_ * T_ * C_);
  // 2. W_attn (2048 x 6144) -> WaT (6144 x 2048) fp16
  k_tconv<<<dim3(C3 / 32, C_ / 32), dim3(32, 8), 0, stream>>>(Wa, WaT, C_, C3);
  // 3. W_proj -> WpT fp16
  k_tconv<<<dim3(C_ / 32, C_ / 32), dim3(32, 8), 0, stream>>>(Wp, WpT, C_, C_);
  // 4. qkv = x @ W_attn + b_attn  (fp16 out): 256x256 tiles, grid 16x24=384 (%8==0)
  k_gemm256<1, 4><<<dim3(384), dim3(512), 0, stream>>>(
      x16, WaT, ba, (void*)qkv16, B_ * T_, C3, C_, 16, 24);
  // 5. RoPE in place on q,k
  k_rope<<<dim3((B_ * T_ * 2048) / 256), dim3(256), 0, stream>>>(qkv16);
  // 6. death times (one wave per (h,j))
  k_death<<<dim3(H_ * T_ / 4), dim3(256), 0, stream>>>(rw, dd);
  // 7. key lists
  k_lists<<<dim3(H_ * T_), dim3(64), 0, stream>>>(dd, lst, cn);
  // 8. sparse attention -> att16 (B,T,C) fp16
  k_attn<<<dim3(B_ * H_ * T_), dim3(64), 0, stream>>>(qkv16, lst, cn, att16);
  // 9. out = att @ W_proj + b_proj (f32 out): 256x128 tiles, grid 16x16=256 (%8==0)
  k_gemm256<0, 2><<<dim3(256), dim3(512), 0, stream>>>(
      att16, WpT, bp, d_out, B_ * T_, C_, C_, 16, 16);
}

// Round 7
// 361.986 us; speedup vs baseline: 2.1164x; 1.0303x over previous
//
#include <hip/hip_runtime.h>
#include <stdint.h>

#define B_ 2
#define T_ 2048
#define C_ 2048
#define H_ 16
#define D_ 128
#define KSP 64
#define C3 6144   // 3*C_

typedef __attribute__((ext_vector_type(4))) float f32x4;
typedef __attribute__((ext_vector_type(8))) _Float16 f16x8;
typedef __attribute__((ext_vector_type(4))) _Float16 f16x4;
typedef __attribute__((ext_vector_type(2))) _Float16 f16x2;

// global -> LDS async copy, 16B per lane. LDS dest is wave-uniform base + lane*16.
__device__ __forceinline__ void gload16(const void* g, void* l) {
  __builtin_amdgcn_global_load_lds(
      (__attribute__((address_space(1))) void*)(uintptr_t)g,
      (__attribute__((address_space(3))) void*)(uint32_t)(uintptr_t)l,
      16, 0, 0);
}

// ---------------- elementwise f32 -> f16 ----------------
__global__ void k_cvt(const float* __restrict__ in, _Float16* __restrict__ out, int n) {
  int i = (blockIdx.x * blockDim.x + threadIdx.x) * 4;
  if (i >= n) return;
  const float4 v = *(const float4*)(in + i);
  f16x4 o;
  o.x = (_Float16)v.x; o.y = (_Float16)v.y; o.z = (_Float16)v.z; o.w = (_Float16)v.w;
  *(f16x4*)(out + i) = o;
}

// ---------------- transpose + convert: W (K x N) f32 -> WT (N x K) f16 ----------------
__global__ void k_tconv(const float* __restrict__ W, _Float16* __restrict__ WT, int K, int N) {
  __shared__ float tile[32][33];
  const int n0 = blockIdx.x * 32, k0 = blockIdx.y * 32;
  const int tx = threadIdx.x, ty = threadIdx.y;  // 32 x 8
#pragma unroll
  for (int r = 0; r < 4; ++r)
    tile[ty + r * 8][tx] = W[(size_t)(k0 + ty + r * 8) * N + n0 + tx];
  __syncthreads();
#pragma unroll
  for (int r = 0; r < 4; ++r)
    WT[(size_t)(n0 + ty + r * 8) * K + k0 + tx] = (_Float16)tile[tx][ty + r * 8];
}

// ---------------- fp16 MFMA GEMM, 8-phase pipelined: C = A(MxK) * BT(NxK)^T + bias -------------
// BM=256, BK=64, 8 waves (2M x 4N), BN = 64*NJ. 4 phases per K-tile:
//   phase = { ds_read sub-frags ; issue next-tile gloads ; s_barrier ; lgkmcnt(0)+sched_barrier ;
//             setprio(1) ; 4*NJ MFMA ; setprio(0) ; s_barrier }
// Stage(t+1) -> other slot, issued phases 0-1 of tile t (slot freed at tile t-1 close -> race-safe);
// single vmcnt(0) at tile end (~3 phases after issue -> zero-wait counted-style).
// T2: 8-granule rotation phys=(lg+row&7)&7; linear LDS dest, inverse-rotated global source,
//     rotated read. T5: setprio around MFMA. T1: XCD-bijective block swizzle (nwg%8==0).
template <int F16OUT, int NJ>
__global__ __launch_bounds__(512) void k_gemm256(const _Float16* __restrict__ A,
                                                 const _Float16* __restrict__ BT,
                                                 const float* __restrict__ bias,
                                                 void* __restrict__ Cout,
                                                 int M, int N, int K,
                                                 int nbm, int nbn) {
  constexpr int BN = 64 * NJ;
  __shared__ __align__(16) _Float16 sA[2][256 * 64];
  __shared__ __align__(16) _Float16 sB[2][BN * 64];
  const int tid = threadIdx.x;
  const int lane = tid & 63;
  const int wid = tid >> 6;
  const int wr = wid >> 2;   // 0..1  (M half)
  const int wc = wid & 3;    // 0..3  (N quarter)
  const int lr = lane & 15;
  const int g = lane >> 4;   // 0..3
  const int rot = lr & 7;    // row&7 == lr&7 for all fragment rows (row offsets are mult of 8)
  // XCD-bijective swizzle (nwg % 8 == 0 at both call sites)
  const int nwg = nbm * nbn;
  const int bid = blockIdx.x;
  const int swz = (bid & 7) * (nwg >> 3) + (bid >> 3);
  const int bm = swz / nbn, bn = swz % nbn;
  const size_t arow0 = (size_t)bm * 256;
  const size_t brow0 = (size_t)bn * BN;

  f32x4 acc[8][NJ];
#pragma unroll
  for (int mi = 0; mi < 8; ++mi)
#pragma unroll
    for (int nj = 0; nj < NJ; ++nj) acc[mi][nj] = (f32x4){0.f, 0.f, 0.f, 0.f};

  auto STAGE_A = [&](int slot, int k0) {
#pragma unroll
    for (int r = 0; r < 4; ++r) {                  // 256 rows * 8 granules / 512 thr = 4
      const int u = tid + r * 512;
      const int row = u >> 3, grl = u & 7;
      const int grn = (grl - (row & 7)) & 7;       // inverse rotation on global source
      gload16(A + (arow0 + row) * K + k0 + grn * 8, &sA[slot][u * 8]);
    }
  };
  auto STAGE_B = [&](int slot, int k0) {
#pragma unroll
    for (int r = 0; r < NJ; ++r) {                 // BN*8/512 = NJ rounds
      const int u = tid + r * 512;
      const int row = u >> 3, grl = u & 7;
      const int grn = (grl - (row & 7)) & 7;
      gload16(BT + (brow0 + row) * K + k0 + grn * 8, &sB[slot][u * 8]);
    }
  };

  f16x8 af[4], bf[NJ];
  auto LDA = [&](int slot, int mh, int kk) {
#pragma unroll
    for (int mi = 0; mi < 4; ++mi) {
      const int row = wr * 128 + (mh * 4 + mi) * 16 + lr;
      af[mi] = *(const f16x8*)&sA[slot][row * 64 + (((kk * 4 + g + rot) & 7) << 3)];
    }
  };
  auto LDB = [&](int slot, int kk) {
#pragma unroll
    for (int nj = 0; nj < NJ; ++nj) {
      const int row = wc * (16 * NJ) + nj * 16 + lr;
      bf[nj] = *(const f16x8*)&sB[slot][row * 64 + (((kk * 4 + g + rot) & 7) << 3)];
    }
  };
  auto MFMAB = [&](int mh) {
    __builtin_amdgcn_s_setprio(1);
#pragma unroll
    for (int mi = 0; mi < 4; ++mi)
#pragma unroll
      for (int nj = 0; nj < NJ; ++nj)
        acc[mh * 4 + mi][nj] =
            __builtin_amdgcn_mfma_f32_16x16x32_f16(af[mi], bf[nj], acc[mh * 4 + mi][nj], 0, 0, 0);
    __builtin_amdgcn_s_setprio(0);
    __builtin_amdgcn_sched_barrier(0);
  };

  STAGE_A(0, 0);
  STAGE_B(0, 0);
  asm volatile("s_waitcnt vmcnt(0)" ::: "memory");
  __builtin_amdgcn_s_barrier();

  const int NT = K >> 6;
  for (int t = 0; t < NT; ++t) {
    const int s = t & 1, ns = s ^ 1;
    const bool pf = (t + 1 < NT);
    const int kn = (t + 1) << 6;
    // ---- phase 0: kk0, rows 0-3 (+B kk0) ; stage A(t+1)
    LDB(s, 0);
    LDA(s, 0, 0);
    if (pf) STAGE_A(ns, kn);
    __builtin_amdgcn_s_barrier();
    asm volatile("s_waitcnt lgkmcnt(0)" ::: "memory");
    __builtin_amdgcn_sched_barrier(0);
    MFMAB(0);
    __builtin_amdgcn_s_barrier();
    // ---- phase 1: kk0, rows 4-7 ; stage B(t+1)
    LDA(s, 1, 0);
    if (pf) STAGE_B(ns, kn);
    __builtin_amdgcn_s_barrier();
    asm volatile("s_waitcnt lgkmcnt(0)" ::: "memory");
    __builtin_amdgcn_sched_barrier(0);
    MFMAB(1);
    __builtin_amdgcn_s_barrier();
    // ---- phase 2: kk1, rows 0-3 (+B kk1)
    LDB(s, 1);
    LDA(s, 0, 1);
    __builtin_amdgcn_s_barrier();
    asm volatile("s_waitcnt lgkmcnt(0)" ::: "memory");
    __builtin_amdgcn_sched_barrier(0);
    MFMAB(0);
    __builtin_amdgcn_s_barrier();
    // ---- phase 3: kk1, rows 4-7 ; tile-end vmcnt drain (t+1's loads, issued ~3 phases ago)
    LDA(s, 1, 1);
    __builtin_amdgcn_s_barrier();
    asm volatile("s_waitcnt lgkmcnt(0)" ::: "memory");
    __builtin_amdgcn_sched_barrier(0);
    MFMAB(1);
    asm volatile("s_waitcnt vmcnt(0)" ::: "memory");
    __builtin_amdgcn_s_barrier();
  }
  // epilogue: C/D layout row = g*4 + r, col = lr (per 16x16 fragment)
  const size_t row0 = arow0 + wr * 128;
  const size_t col0 = brow0 + wc * (16 * NJ);
#pragma unroll
  for (int mi = 0; mi < 8; ++mi) {
#pragma unroll
    for (int nj = 0; nj < NJ; ++nj) {
      const size_t col = col0 + nj * 16 + lr;
      const float bv = bias[col];
#pragma unroll
      for (int r = 0; r < 4; ++r) {
        const size_t row = row0 + mi * 16 + g * 4 + r;
        const float v = acc[mi][nj][r] + bv;
        if (F16OUT)
          ((_Float16*)Cout)[row * N + col] = (_Float16)v;
        else
          ((float*)Cout)[row * N + col] = v;
      }
    }
  }
}

// ---------------- in-place RoPE on q,k sections of qkv (B,T,3C) fp16 ----------------
__global__ void k_rope(_Float16* __restrict__ qkv) {
  const int idx = blockIdx.x * blockDim.x + threadIdx.x;  // exact grid
  const int pp = idx & 2047;   // pair slot within (b,t): [0,1024)=q, [1024,2048)=k
  const int bt = idx >> 11;
  const int t = bt & (T_ - 1);
  const int sec = pp >> 10;
  const int p = pp & 1023;
  const int hh = p >> 6;
  const int dp = p & 63;
  const float freq = expf(-0.14391156831212787f * (float)dp);  // 10000^(-dp/64)
  const float ang = (float)t * freq;
  float sn, cs;
  sincosf(ang, &sn, &cs);
  const size_t base = (size_t)bt * C3 + (size_t)sec * C_ + hh * D_ + 2 * dp;
  f16x2 v = *(f16x2*)(qkv + base);
  const float xe = (float)v.x, xo = (float)v.y;
  f16x2 o;
  o.x = (_Float16)(xe * cs - xo * sn);
  o.y = (_Float16)(xe * sn + xo * cs);
  *(f16x2*)(qkv + base) = o;
}

// ---------------- death time d[h][j]: index of 64th beater (T if <64 beaters) ----------------
// One WAVE per (h,j): ballot-based ordered count, <=32 wave-parallel steps.
__global__ __launch_bounds__(256) void k_death(const float* __restrict__ rw, int* __restrict__ dd) {
  const int widG = blockIdx.x * 4 + (threadIdx.x >> 6);  // global wave id = h*T_ + j
  const int lane = threadIdx.x & 63;
  const int h = widG >> 11, j = widG & (T_ - 1);
  const float* s = rw + h * T_;
  const float sj = s[j];
  int total = 0, d = T_;
  for (int base = 0; base < T_; base += 64) {
    const int t = base + lane;
    const float st = s[t];
    const bool beat = (st > sj) || (st == sj && t < j);
    const unsigned long long bal = __ballot(beat);
    const int c = __popcll(bal);
    if (total + c >= KSP) {  // wave-uniform condition
      const int need = KSP - total;  // 1-based rank within this chunk
      const int p = __popcll(bal & ((1ull << lane) - 1ull));
      const unsigned long long win = __ballot(beat && (p == need - 1));
      d = base + __builtin_ctzll(win);
      break;
    }
    total += c;
  }
  if (lane == 0) dd[widG] = d;
}

// ---------------- key lists: one wave per (h,i), ballot-compact {j<=i : d[h,j]>i} ----------------
__global__ __launch_bounds__(64) void k_lists(const int* __restrict__ dd,
                                              int* __restrict__ lst,
                                              int* __restrict__ cnt) {
  const int bid = blockIdx.x;  // h*T + i
  const int i = bid & (T_ - 1);
  const int h = bid >> 11;
  const int lane = threadIdx.x;
  const int* dh = dd + h * T_;
  int total = 0;
  for (int base = 0; base <= i; base += 64) {
    const int jx = base + lane;
    const bool pred = (jx <= i) && (dh[jx] > i);
    const unsigned long long bal = __ballot(pred);
    const int pos = total + __popcll(bal & ((1ull << lane) - 1ull));
    if (pred && pos < KSP) lst[(size_t)bid * KSP + pos] = jx;
    total += __popcll(bal);
  }
  if (lane == 0) cnt[bid] = total < KSP ? total : KSP;
}

// ---------------- sparse attention: one wave per (b,h,i) ----------------
// Phase 1 (coalesced-transposed): lane = g*16+l (g: key subgroup 0..3, l: 8-dim chunk).
// Phase 2: half-wave split, 2x16 batched coalesced V loads.
__global__ __launch_bounds__(64) void k_attn(const _Float16* __restrict__ qkv,
                                             const int* __restrict__ lst,
                                             const int* __restrict__ cnt,
                                             _Float16* __restrict__ out) {
  __shared__ uint2 spair[64];  // {bitcast(p), v-row element offset}
  const int bid = blockIdx.x;  // b*H*T + h*T + i
  const int i = bid & (T_ - 1);
  const int h = (bid >> 11) & (H_ - 1);
  const int b = bid >> 15;
  const int lane = threadIdx.x;
  const int g = lane >> 4;       // key subgroup
  const int l = lane & 15;       // dim chunk
  const int c = cnt[(h << 11) + i];
  const int* mylst = lst + ((size_t)((h << 11) + i)) * KSP;
  // owned slot: s_own = l*4 + g  (bijection over 64 slots)
  const int s_own = l * 4 + g;
  const int j_own = (s_own < c) ? mylst[s_own] : 0;
  // q chunk for this lane's dim group (broadcast across g)
  const _Float16* qkvb = qkv + (size_t)b * T_ * C3;
  const f16x8 qv = *(const f16x8*)(qkvb + (size_t)i * C3 + h * D_ + l * 8);
  const f16x2 q0 = __builtin_shufflevector(qv, qv, 0, 1);
  const f16x2 q1 = __builtin_shufflevector(qv, qv, 2, 3);
  const f16x2 q2 = __builtin_shufflevector(qv, qv, 4, 5);
  const f16x2 q3 = __builtin_shufflevector(qv, qv, 6, 7);
  const _Float16* kbase = qkvb + C_ + h * D_ + l * 8;
  float p[16];
#pragma unroll
  for (int hf = 0; hf < 2; ++hf) {
    f16x8 vk[8];
#pragma unroll
    for (int u = 0; u < 8; ++u) {
      const int kb = hf * 8 + u;
      const int jk = __shfl(j_own, (lane & 48) + kb);  // owner lane of slot kb*4+g
      vk[u] = *(const f16x8*)(kbase + (size_t)jk * C3);
    }
#pragma unroll
    for (int u = 0; u < 8; ++u) {
      float a0 = 0.f, a1 = 0.f;
#if __has_builtin(__builtin_amdgcn_fdot2)
      a0 = __builtin_amdgcn_fdot2(q0, __builtin_shufflevector(vk[u], vk[u], 0, 1), a0, false);
      a1 = __builtin_amdgcn_fdot2(q1, __builtin_shufflevector(vk[u], vk[u], 2, 3), a1, false);
      a0 = __builtin_amdgcn_fdot2(q2, __builtin_shufflevector(vk[u], vk[u], 4, 5), a0, false);
      a1 = __builtin_amdgcn_fdot2(q3, __builtin_shufflevector(vk[u], vk[u], 6, 7), a1, false);
#else
#pragma unroll
      for (int t = 0; t < 8; t += 2) {
        a0 += (float)qv[t] * (float)vk[u][t];
        a1 += (float)qv[t + 1] * (float)vk[u][t + 1];
      }
#endif
      p[hf * 8 + u] = a0 + a1;
    }
  }
  // reduce over dim-chunks (lanes with same g), mask invalid slots, scale
#pragma unroll
  for (int kb = 0; kb < 16; ++kb) {
    float t = p[kb];
    t += __shfl_xor(t, 1);
    t += __shfl_xor(t, 2);
    t += __shfl_xor(t, 4);
    t += __shfl_xor(t, 8);
    p[kb] = (kb * 4 + g < c) ? t * 0.08838834764831845f : -INFINITY;
  }
  // wave max
  float m = p[0];
#pragma unroll
  for (int kb = 1; kb < 16; ++kb) m = fmaxf(m, p[kb]);
  m = fmaxf(m, __shfl_xor(m, 16));
  m = fmaxf(m, __shfl_xor(m, 32));
  // wave sum of exps
  float ssum = 0.f;
#pragma unroll
  for (int kb = 0; kb < 16; ++kb) ssum += __expf(p[kb] - m);
  ssum += __shfl_xor(ssum, 16);
  ssum += __shfl_xor(ssum, 32);
  // select own slot's score (compile-time-indexed cndmask chain)
  float pown = p[0];
#pragma unroll
  for (int kb = 1; kb < 16; ++kb) pown = (l == kb) ? p[kb] : pown;
  const float pfin = __expf(pown - m) / ssum;
  spair[s_own] = make_uint2(__float_as_uint(pfin), (uint32_t)(j_own * C3));
  __syncthreads();  // single-wave block: compiles to waitcnt
  // phase 2: half-wave over key slots, 4 dims per lane, 2 chunks of 16.
  const int half = lane >> 5;
  const int dl = lane & 31;
  const int jbeg = half << 5;
  const _Float16* vbase = qkvb + 2 * C_ + h * D_ + 4 * dl;
  float o0 = 0.f, o1 = 0.f, o2 = 0.f, o3 = 0.f;
#pragma unroll
  for (int ch = 0; ch < 2; ++ch) {
    float pj[16];
    f16x4 vv[16];
#pragma unroll
    for (int u = 0; u < 16; ++u) {
      const uint2 pr = spair[jbeg + ch * 16 + u];
      pj[u] = __uint_as_float(pr.x);
      vv[u] = *(const f16x4*)(vbase + pr.y);
    }
#pragma unroll
    for (int u = 0; u < 16; ++u) {
      o0 += pj[u] * (float)vv[u].x;
      o1 += pj[u] * (float)vv[u].y;
      o2 += pj[u] * (float)vv[u].z;
      o3 += pj[u] * (float)vv[u].w;
    }
  }
  o0 += __shfl_xor(o0, 32);
  o1 += __shfl_xor(o1, 32);
  o2 += __shfl_xor(o2, 32);
  o3 += __shfl_xor(o3, 32);
  if (half == 0) {
    f16x4 ov;
    ov.x = (_Float16)o0;
    ov.y = (_Float16)o1;
    ov.z = (_Float16)o2;
    ov.w = (_Float16)o3;
    *(f16x4*)(out + (size_t)(b * T_ + i) * C_ + h * D_ + 4 * dl) = ov;
  }
}

extern "C" void kernel_launch(void* const* d_in, const int* in_sizes, int n_in,
                              void* d_out, int out_size, void* d_ws, size_t ws_size,
                              hipStream_t stream) {
  const float* x  = (const float*)d_in[0];
  const float* Wa = (const float*)d_in[1];
  const float* ba = (const float*)d_in[2];
  const float* Wp = (const float*)d_in[3];
  const float* bp = (const float*)d_in[4];
  const float* rw = (const float*)d_in[5];

  char* ws = (char*)d_ws;
  _Float16* qkv16 = (_Float16*)(ws);                              // 48 MB
  _Float16* WaT   = (_Float16*)(ws + (size_t)48 * 1024 * 1024);   // 24 MB
  _Float16* WpT   = (_Float16*)(ws + (size_t)72 * 1024 * 1024);   //  8 MB
  _Float16* x16   = (_Float16*)(ws + (size_t)80 * 1024 * 1024);   // 16 MB (reused as att16)
  int* dd  = (int*)(ws + (size_t)96 * 1024 * 1024);               // 128 KB
  int* cn  = (int*)(ws + (size_t)96 * 1024 * 1024 + (1 << 17));   // 128 KB
  int* lst = (int*)(ws + (size_t)96 * 1024 * 1024 + (2 << 17));   //  8 MB
  _Float16* att16 = x16;  // x16 dead after GEMM1; total ws use ~104.5 MB

  // 1. x -> fp16
  k_cvt<<<dim3((B_ * T_ * C_) / 1024), dim3(256), 0, stream>>>(x, x16, B_ * T_ * C_);
  // 2. W_attn (2048 x 6144) -> WaT (6144 x 2048) fp16
  k_tconv<<<dim3(C3 / 32, C_ / 32), dim3(32, 8), 0, stream>>>(Wa, WaT, C_, C3);
  // 3. W_proj -> WpT fp16
  k_tconv<<<dim3(C_ / 32, C_ / 32), dim3(32, 8), 0, stream>>>(Wp, WpT, C_, C_);
  // 4. qkv = x @ W_attn + b_attn (fp16 out): 256x192 tiles, grid 16x32=512 = 2 exact rounds
  k_gemm256<1, 3><<<dim3(512), dim3(512), 0, stream>>>(
      x16, WaT, ba, (void*)qkv16, B_ * T_, C3, C_, 16, 32);
  // 5. RoPE in place on q,k
  k_rope<<<dim3((B_ * T_ * 2048) / 256), dim3(256), 0, stream>>>(qkv16);
  // 6. death times (one wave per (h,j))
  k_death<<<dim3(H_ * T_ / 4), dim3(256), 0, stream>>>(rw, dd);
  // 7. key lists
  k_lists<<<dim3(H_ * T_), dim3(64), 0, stream>>>(dd, lst, cn);
  // 8. sparse attention -> att16 (B,T,C) fp16
  k_attn<<<dim3(B_ * H_ * T_), dim3(64), 0, stream>>>(qkv16, lst, cn, att16);
  // 9. out = att @ W_proj + b_proj (f32 out): 256x128 tiles, grid 16x16=256 = 1 round
  k_gemm256<0, 2><<<dim3(256), dim3(512), 0, stream>>>(
      att16, WpT, bp, d_out, B_ * T_, C_, C_, 16, 16);
}

// Round 9
// 255.587 us; speedup vs baseline: 2.9975x; 1.4163x over previous
//
#include <hip/hip_runtime.h>
#include <stdint.h>

#define B_ 2
#define T_ 2048
#define C_ 2048
#define H_ 16
#define D_ 128
#define KSP 64
#define C3 6144   // 3*C_

typedef __attribute__((ext_vector_type(4))) float f32x4;
typedef __attribute__((ext_vector_type(8))) _Float16 f16x8;
typedef __attribute__((ext_vector_type(4))) _Float16 f16x4;
typedef __attribute__((ext_vector_type(2))) _Float16 f16x2;

// global -> LDS async copy, 16B per lane. LDS dest is wave-uniform base + lane*16.
__device__ __forceinline__ void gload16(const void* g, void* l) {
  __builtin_amdgcn_global_load_lds(
      (__attribute__((address_space(1))) void*)(uintptr_t)g,
      (__attribute__((address_space(3))) void*)(uint32_t)(uintptr_t)l,
      16, 0, 0);
}

// ---------------- elementwise f32 -> f16 ----------------
__global__ void k_cvt(const float* __restrict__ in, _Float16* __restrict__ out, int n) {
  int i = (blockIdx.x * blockDim.x + threadIdx.x) * 4;
  if (i >= n) return;
  const float4 v = *(const float4*)(in + i);
  f16x4 o;
  o.x = (_Float16)v.x; o.y = (_Float16)v.y; o.z = (_Float16)v.z; o.w = (_Float16)v.w;
  *(f16x4*)(out + i) = o;
}

// ---------------- transpose + convert: W (K x N) f32 -> WT (N x K) f16 ----------------
__global__ void k_tconv(const float* __restrict__ W, _Float16* __restrict__ WT, int K, int N) {
  __shared__ float tile[32][33];
  const int n0 = blockIdx.x * 32, k0 = blockIdx.y * 32;
  const int tx = threadIdx.x, ty = threadIdx.y;  // 32 x 8
#pragma unroll
  for (int r = 0; r < 4; ++r)
    tile[ty + r * 8][tx] = W[(size_t)(k0 + ty + r * 8) * N + n0 + tx];
  __syncthreads();
#pragma unroll
  for (int r = 0; r < 4; ++r)
    WT[(size_t)(n0 + ty + r * 8) * K + k0 + tx] = (_Float16)tile[tx][ty + r * 8];
}

// ---------------- fp16 MFMA GEMM, 8-phase pipelined (unchanged from R6) ----------------
template <int F16OUT, int NJ>
__global__ __launch_bounds__(512) void k_gemm256(const _Float16* __restrict__ A,
                                                 const _Float16* __restrict__ BT,
                                                 const float* __restrict__ bias,
                                                 void* __restrict__ Cout,
                                                 int M, int N, int K,
                                                 int nbm, int nbn) {
  constexpr int BN = 64 * NJ;
  __shared__ __align__(16) _Float16 sA[2][256 * 64];
  __shared__ __align__(16) _Float16 sB[2][BN * 64];
  const int tid = threadIdx.x;
  const int lane = tid & 63;
  const int wid = tid >> 6;
  const int wr = wid >> 2;
  const int wc = wid & 3;
  const int lr = lane & 15;
  const int g = lane >> 4;
  const int rot = lr & 7;
  const int nwg = nbm * nbn;
  const int bid = blockIdx.x;
  const int swz = (bid & 7) * (nwg >> 3) + (bid >> 3);
  const int bm = swz / nbn, bn = swz % nbn;
  const size_t arow0 = (size_t)bm * 256;
  const size_t brow0 = (size_t)bn * BN;

  f32x4 acc[8][NJ];
#pragma unroll
  for (int mi = 0; mi < 8; ++mi)
#pragma unroll
    for (int nj = 0; nj < NJ; ++nj) acc[mi][nj] = (f32x4){0.f, 0.f, 0.f, 0.f};

  auto STAGE_A = [&](int slot, int k0) {
#pragma unroll
    for (int r = 0; r < 4; ++r) {
      const int u = tid + r * 512;
      const int row = u >> 3, grl = u & 7;
      const int grn = (grl - (row & 7)) & 7;
      gload16(A + (arow0 + row) * K + k0 + grn * 8, &sA[slot][u * 8]);
    }
  };
  auto STAGE_B = [&](int slot, int k0) {
#pragma unroll
    for (int r = 0; r < NJ; ++r) {
      const int u = tid + r * 512;
      const int row = u >> 3, grl = u & 7;
      const int grn = (grl - (row & 7)) & 7;
      gload16(BT + (brow0 + row) * K + k0 + grn * 8, &sB[slot][u * 8]);
    }
  };

  f16x8 af[4], bf[NJ];
  auto LDA = [&](int slot, int mh, int kk) {
#pragma unroll
    for (int mi = 0; mi < 4; ++mi) {
      const int row = wr * 128 + (mh * 4 + mi) * 16 + lr;
      af[mi] = *(const f16x8*)&sA[slot][row * 64 + (((kk * 4 + g + rot) & 7) << 3)];
    }
  };
  auto LDB = [&](int slot, int kk) {
#pragma unroll
    for (int nj = 0; nj < NJ; ++nj) {
      const int row = wc * (16 * NJ) + nj * 16 + lr;
      bf[nj] = *(const f16x8*)&sB[slot][row * 64 + (((kk * 4 + g + rot) & 7) << 3)];
    }
  };
  auto MFMAB = [&](int mh) {
    __builtin_amdgcn_s_setprio(1);
#pragma unroll
    for (int mi = 0; mi < 4; ++mi)
#pragma unroll
      for (int nj = 0; nj < NJ; ++nj)
        acc[mh * 4 + mi][nj] =
            __builtin_amdgcn_mfma_f32_16x16x32_f16(af[mi], bf[nj], acc[mh * 4 + mi][nj], 0, 0, 0);
    __builtin_amdgcn_s_setprio(0);
    __builtin_amdgcn_sched_barrier(0);
  };

  STAGE_A(0, 0);
  STAGE_B(0, 0);
  asm volatile("s_waitcnt vmcnt(0)" ::: "memory");
  __builtin_amdgcn_s_barrier();

  const int NT = K >> 6;
  for (int t = 0; t < NT; ++t) {
    const int s = t & 1, ns = s ^ 1;
    const bool pf = (t + 1 < NT);
    const int kn = (t + 1) << 6;
    LDB(s, 0);
    LDA(s, 0, 0);
    if (pf) STAGE_A(ns, kn);
    __builtin_amdgcn_s_barrier();
    asm volatile("s_waitcnt lgkmcnt(0)" ::: "memory");
    __builtin_amdgcn_sched_barrier(0);
    MFMAB(0);
    __builtin_amdgcn_s_barrier();
    LDA(s, 1, 0);
    if (pf) STAGE_B(ns, kn);
    __builtin_amdgcn_s_barrier();
    asm volatile("s_waitcnt lgkmcnt(0)" ::: "memory");
    __builtin_amdgcn_sched_barrier(0);
    MFMAB(1);
    __builtin_amdgcn_s_barrier();
    LDB(s, 1);
    LDA(s, 0, 1);
    __builtin_amdgcn_s_barrier();
    asm volatile("s_waitcnt lgkmcnt(0)" ::: "memory");
    __builtin_amdgcn_sched_barrier(0);
    MFMAB(0);
    __builtin_amdgcn_s_barrier();
    LDA(s, 1, 1);
    __builtin_amdgcn_s_barrier();
    asm volatile("s_waitcnt lgkmcnt(0)" ::: "memory");
    __builtin_amdgcn_sched_barrier(0);
    MFMAB(1);
    asm volatile("s_waitcnt vmcnt(0)" ::: "memory");
    __builtin_amdgcn_s_barrier();
  }
  const size_t row0 = arow0 + wr * 128;
  const size_t col0 = brow0 + wc * (16 * NJ);
#pragma unroll
  for (int mi = 0; mi < 8; ++mi) {
#pragma unroll
    for (int nj = 0; nj < NJ; ++nj) {
      const size_t col = col0 + nj * 16 + lr;
      const float bv = bias[col];
#pragma unroll
      for (int r = 0; r < 4; ++r) {
        const size_t row = row0 + mi * 16 + g * 4 + r;
        const float v = acc[mi][nj][r] + bv;
        if (F16OUT)
          ((_Float16*)Cout)[row * N + col] = (_Float16)v;
        else
          ((float*)Cout)[row * N + col] = v;
      }
    }
  }
}

// ---------------- in-place RoPE on q,k sections of qkv (B,T,3C) fp16 ----------------
__global__ void k_rope(_Float16* __restrict__ qkv) {
  const int idx = blockIdx.x * blockDim.x + threadIdx.x;
  const int pp = idx & 2047;
  const int bt = idx >> 11;
  const int t = bt & (T_ - 1);
  const int sec = pp >> 10;
  const int p = pp & 1023;
  const int hh = p >> 6;
  const int dp = p & 63;
  const float freq = expf(-0.14391156831212787f * (float)dp);
  const float ang = (float)t * freq;
  float sn, cs;
  sincosf(ang, &sn, &cs);
  const size_t base = (size_t)bt * C3 + (size_t)sec * C_ + hh * D_ + 2 * dp;
  f16x2 v = *(f16x2*)(qkv + base);
  const float xe = (float)v.x, xo = (float)v.y;
  f16x2 o;
  o.x = (_Float16)(xe * cs - xo * sn);
  o.y = (_Float16)(xe * sn + xo * cs);
  *(f16x2*)(qkv + base) = o;
}

// ---------------- death time d[h][j]: index of 64th beater (T if <64 beaters) ----------------
__global__ __launch_bounds__(256) void k_death(const float* __restrict__ rw, int* __restrict__ dd) {
  const int widG = blockIdx.x * 4 + (threadIdx.x >> 6);
  const int lane = threadIdx.x & 63;
  const int h = widG >> 11, j = widG & (T_ - 1);
  const float* s = rw + h * T_;
  const float sj = s[j];
  int total = 0, d = T_;
  for (int base = 0; base < T_; base += 64) {
    const int t = base + lane;
    const float st = s[t];
    const bool beat = (st > sj) || (st == sj && t < j);
    const unsigned long long bal = __ballot(beat);
    const int c = __popcll(bal);
    if (total + c >= KSP) {
      const int need = KSP - total;
      const int p = __popcll(bal & ((1ull << lane) - 1ull));
      const unsigned long long win = __ballot(beat && (p == need - 1));
      d = base + __builtin_ctzll(win);
      break;
    }
    total += c;
  }
  if (lane == 0) dd[widG] = d;
}

// ---------------- superset key lists per (h, 16-query block) ----------------
// superset = {j <= i1 : d[h,j] > i0}, |.| <= 79 < 96. pk = j | (d<<12). pad pk=0 (self-masking).
__global__ __launch_bounds__(64) void k_slist(const int* __restrict__ dd,
                                              uint32_t* __restrict__ slist) {
  const int bid = blockIdx.x;  // h*128 + qb
  const int qb = bid & 127, h = bid >> 7;
  const int i0 = qb * 16, i1 = i0 + 15;
  const int lane = threadIdx.x;
  const int* dh = dd + h * T_;
  uint32_t* lb = slist + (size_t)bid * 96;
  int total = 0;
  for (int base = 0; base <= i1; base += 64) {
    const int j = base + lane;
    const int dv = dh[j];
    const bool pred = (j <= i1) && (dv > i0);
    const unsigned long long bal = __ballot(pred);
    const int pos = total + __popcll(bal & ((1ull << lane) - 1ull));
    if (pred) lb[pos] = (uint32_t)j | ((uint32_t)dv << 12);
    total += __popcll(bal);
  }
  for (int s = total + lane; s < 96; s += 64) lb[s] = 0;
}

// ---------------- MFMA sparse attention: one wave per (b, h, 16 queries) ----------------
// Swapped QK^T: S^T = mfma(A=K-rows, B=Q-rows) -> lane owns all 24 scores of query i0+(lane&15).
// Mask from pk in LDS. P -> f16 -> Pl[16][104] (stride-104, 2-way-free). PV: out = mfma(A=P, B=V),
// V staged per 4KB chunk with scatter-transpose writes, bank-rotated by sigma=(lt>>3)|((mt&1)<<1)
// XOR'd into the g-granule coordinate on BOTH write and read.
__global__ __launch_bounds__(64, 4) void k_mattn(const _Float16* __restrict__ qkv,
                                                 const uint32_t* __restrict__ slist,
                                                 _Float16* __restrict__ out) {
  __shared__ uint32_t jd[96];
  __shared__ int joff[96];
  __shared__ __align__(16) _Float16 Pl[16 * 104];
  __shared__ __align__(16) _Float16 VT[2048];  // [mt4][lt16][gt4][e8] per (cc,dh) chunk
  const int bid = blockIdx.x;  // b*2048 + h*128 + qb
  const int qb = bid & 127, h = (bid >> 7) & 15, b = bid >> 11;
  const int i0 = qb * 16;
  const int lane = threadIdx.x;
  const int g = lane >> 4, l = lane & 15;
  const uint32_t* lb = slist + (size_t)((h << 7) + qb) * 96;
  {
    const uint32_t pk = lb[lane];
    jd[lane] = pk;
    joff[lane] = (int)(pk & 0xFFFu) * C3;
    if (lane < 32) {
      const uint32_t pk1 = lb[64 + lane];
      jd[64 + lane] = pk1;
      joff[64 + lane] = (int)(pk1 & 0xFFFu) * C3;
    }
  }
  __syncthreads();
  const _Float16* qkvb = qkv + (size_t)b * T_ * C3;
  // Q B-frags: lane gives Q[query=i0+l][dims 32c+8g+0..7]
  const _Float16* qrow = qkvb + (size_t)(i0 + l) * C3 + h * D_ + 8 * g;
  f16x8 bq[4];
#pragma unroll
  for (int c = 0; c < 4; ++c) bq[c] = *(const f16x8*)(qrow + 32 * c);
  // scores: per 16-slot tile t: A-frag = K[slot 16t+l][32c+8g..]
  f32x4 sacc[6];
  const _Float16* kbase = qkvb + C_ + h * D_ + 8 * g;
#pragma unroll
  for (int t = 0; t < 6; ++t) {
    const int jo = joff[16 * t + l];
    const _Float16* kr = kbase + jo;
    f16x8 ak[4];
#pragma unroll
    for (int c = 0; c < 4; ++c) ak[c] = *(const f16x8*)(kr + 32 * c);
    f32x4 a = {0.f, 0.f, 0.f, 0.f};
#pragma unroll
    for (int c = 0; c < 4; ++c)
      a = __builtin_amdgcn_mfma_f32_16x16x32_f16(ak[c], bq[c], a, 0, 0, 0);
    sacc[t] = a;  // S^T[slot 16t+4g+r][query i0+l]
  }
  // mask + softmax: lane's 24 values all belong to query iq = i0+l
  const int iq = i0 + l;
  float P[6][4];
  float m = -INFINITY;
#pragma unroll
  for (int t = 0; t < 6; ++t)
#pragma unroll
    for (int r = 0; r < 4; ++r) {
      const uint32_t pk = jd[16 * t + 4 * g + r];
      const int j = (int)(pk & 0xFFFu);
      const int d = (int)(pk >> 12);
      const bool ok = (j <= iq) && (d > iq);
      const float x = ok ? sacc[t][r] * 0.08838834764831845f : -INFINITY;
      P[t][r] = x;
      m = fmaxf(m, x);
    }
  m = fmaxf(m, __shfl_xor(m, 16));
  m = fmaxf(m, __shfl_xor(m, 32));
  float ssum = 0.f;
#pragma unroll
  for (int t = 0; t < 6; ++t)
#pragma unroll
    for (int r = 0; r < 4; ++r) {
      const float e = __expf(P[t][r] - m);
      P[t][r] = e;
      ssum += e;
    }
  ssum += __shfl_xor(ssum, 16);
  ssum += __shfl_xor(ssum, 32);
  const float inv = 1.0f / ssum;
  // P (f16, normalized) -> Pl[l][16t+4g+0..3]  (compiler fuses the casts to v_cvt_pkrtz)
#pragma unroll
  for (int t = 0; t < 6; ++t) {
    f16x4 w;
    w.x = (_Float16)(P[t][0] * inv);
    w.y = (_Float16)(P[t][1] * inv);
    w.z = (_Float16)(P[t][2] * inv);
    w.w = (_Float16)(P[t][3] * inv);
    *(f16x4*)&Pl[l * 104 + 16 * t + 4 * g] = w;
  }
  __syncthreads();
  // P A-frags: lane gives P[query=l][slots 32cc+8g+0..7]
  f16x8 pf[3];
#pragma unroll
  for (int cc = 0; cc < 3; ++cc) pf[cc] = *(const f16x8*)&Pl[l * 104 + 32 * cc + 8 * g];
  // PV
  f32x4 oacc[8];
#pragma unroll
  for (int mt = 0; mt < 8; ++mt) oacc[mt] = (f32x4){0.f, 0.f, 0.f, 0.f};
  const _Float16* vbase = qkvb + 2 * C_ + h * D_;
#pragma unroll
  for (int cc = 0; cc < 3; ++cc) {
    const int jo0 = joff[32 * cc + l];       // tau=0: slot 32cc+l
    const int jo1 = joff[32 * cc + 16 + l];  // tau=1: slot 32cc+16+l
#pragma unroll
    for (int dh = 0; dh < 2; ++dh) {
      f16x8 vl0[2], vl1[2];
#pragma unroll
      for (int cp = 0; cp < 2; ++cp) {
        vl0[cp] = *(const f16x8*)(vbase + jo0 + 64 * dh + 32 * cp + 8 * g);
        vl1[cp] = *(const f16x8*)(vbase + jo1 + 64 * dh + 32 * cp + 8 * g);
      }
      __syncthreads();  // previous chunk's reads complete before overwrite
      // scatter-transpose: element (slot=32cc+16tau+l, dim'=32cp+8g+e) ->
      //   VT[mt=2cp+(g>>1)][lt=8(g&1)+e][gt=2tau+(l>>3) ^ sigma][et=l&7], sigma==g here
#pragma unroll
      for (int tau = 0; tau < 2; ++tau)
#pragma unroll
        for (int cp = 0; cp < 2; ++cp) {
          const int mtl = 2 * cp + (g >> 1);
          const int lt0 = 8 * (g & 1);
          const int gt = (2 * tau + (l >> 3)) ^ g;
          const int et = l & 7;
#pragma unroll
          for (int e = 0; e < 8; ++e) {
            const int idx = ((mtl * 16 + lt0 + e) * 4 + gt) * 8 + et;
            VT[idx] = tau ? vl1[cp][e] : vl0[cp][e];
          }
        }
      __syncthreads();
      // V B-frags: lane gives V[slot 32cc+8g+e][dim 64dh+16mtl+l]
#pragma unroll
      for (int mtl = 0; mtl < 4; ++mtl) {
        const int sgr = (l >> 3) | ((mtl & 1) << 1);
        const f16x8 vf = *(const f16x8*)&VT[((mtl * 16 + l) * 4 + (g ^ sgr)) * 8];
        oacc[4 * dh + mtl] =
            __builtin_amdgcn_mfma_f32_16x16x32_f16(pf[cc], vf, oacc[4 * dh + mtl], 0, 0, 0);
      }
    }
  }
  // out[query i0+4g+r][h*128 + 16mt + l]
  _Float16* ob = out + (size_t)(b * T_ + i0 + 4 * g) * C_ + h * D_ + l;
#pragma unroll
  for (int mt = 0; mt < 8; ++mt)
#pragma unroll
    for (int r = 0; r < 4; ++r)
      ob[(size_t)r * C_ + 16 * mt] = (_Float16)oacc[mt][r];
}

extern "C" void kernel_launch(void* const* d_in, const int* in_sizes, int n_in,
                              void* d_out, int out_size, void* d_ws, size_t ws_size,
                              hipStream_t stream) {
  const float* x  = (const float*)d_in[0];
  const float* Wa = (const float*)d_in[1];
  const float* ba = (const float*)d_in[2];
  const float* Wp = (const float*)d_in[3];
  const float* bp = (const float*)d_in[4];
  const float* rw = (const float*)d_in[5];

  char* ws = (char*)d_ws;
  _Float16* qkv16 = (_Float16*)(ws);                              // 48 MB
  _Float16* WaT   = (_Float16*)(ws + (size_t)48 * 1024 * 1024);   // 24 MB
  _Float16* WpT   = (_Float16*)(ws + (size_t)72 * 1024 * 1024);   //  8 MB
  _Float16* x16   = (_Float16*)(ws + (size_t)80 * 1024 * 1024);   // 16 MB (reused as att16)
  int* dd  = (int*)(ws + (size_t)96 * 1024 * 1024);               // 128 KB
  uint32_t* slist = (uint32_t*)(ws + (size_t)96 * 1024 * 1024 + (2 << 17));  // 786 KB
  _Float16* att16 = x16;  // x16 dead after GEMM1

  // 1. x -> fp16
  k_cvt<<<dim3((B_ * T_ * C_) / 1024), dim3(256), 0, stream>>>(x, x16, B_ * T_ * C_);
  // 2. W_attn -> WaT fp16
  k_tconv<<<dim3(C3 / 32, C_ / 32), dim3(32, 8), 0, stream>>>(Wa, WaT, C_, C3);
  // 3. W_proj -> WpT fp16
  k_tconv<<<dim3(C_ / 32, C_ / 32), dim3(32, 8), 0, stream>>>(Wp, WpT, C_, C_);
  // 4. qkv = x @ W_attn + b_attn (fp16 out): 256x192 tiles, grid 512 = 2 exact rounds
  k_gemm256<1, 3><<<dim3(512), dim3(512), 0, stream>>>(
      x16, WaT, ba, (void*)qkv16, B_ * T_, C3, C_, 16, 32);
  // 5. RoPE in place on q,k
  k_rope<<<dim3((B_ * T_ * 2048) / 256), dim3(256), 0, stream>>>(qkv16);
  // 6. death times
  k_death<<<dim3(H_ * T_ / 4), dim3(256), 0, stream>>>(rw, dd);
  // 7. superset key lists per (h, 16-query block)
  k_slist<<<dim3(H_ * (T_ / 16)), dim3(64), 0, stream>>>(dd, slist);
  // 8. MFMA sparse attention -> att16
  k_mattn<<<dim3(B_ * H_ * (T_ / 16)), dim3(64), 0, stream>>>(qkv16, slist, att16);
  // 9. out = att @ W_proj + b_proj (f32 out): 256x128 tiles, grid 256 = 1 round
  k_gemm256<0, 2><<<dim3(256), dim3(512), 0, stream>>>(
      att16, WpT, bp, d_out, B_ * T_, C_, C_, 16, 16);
}

// Round 10
// 247.649 us; speedup vs baseline: 3.0936x; 1.0321x over previous
//
#include <hip/hip_runtime.h>
#include <stdint.h>

#define B_ 2
#define T_ 2048
#define C_ 2048
#define H_ 16
#define D_ 128
#define KSP 64
#define C3 6144   // 3*C_

typedef __attribute__((ext_vector_type(4))) float f32x4;
typedef __attribute__((ext_vector_type(8))) _Float16 f16x8;
typedef __attribute__((ext_vector_type(4))) _Float16 f16x4;
typedef __attribute__((ext_vector_type(2))) _Float16 f16x2;

// global -> LDS async copy, 16B per lane. LDS dest is wave-uniform base + lane*16.
__device__ __forceinline__ void gload16(const void* g, void* l) {
  __builtin_amdgcn_global_load_lds(
      (__attribute__((address_space(1))) void*)(uintptr_t)g,
      (__attribute__((address_space(3))) void*)(uint32_t)(uintptr_t)l,
      16, 0, 0);
}

// ---------------- elementwise f32 -> f16 ----------------
__global__ void k_cvt(const float* __restrict__ in, _Float16* __restrict__ out, int n) {
  int i = (blockIdx.x * blockDim.x + threadIdx.x) * 4;
  if (i >= n) return;
  const float4 v = *(const float4*)(in + i);
  f16x4 o;
  o.x = (_Float16)v.x; o.y = (_Float16)v.y; o.z = (_Float16)v.z; o.w = (_Float16)v.w;
  *(f16x4*)(out + i) = o;
}

// ---------------- transpose + convert: W (K x N) f32 -> WT (N x K) f16 ----------------
__global__ void k_tconv(const float* __restrict__ W, _Float16* __restrict__ WT, int K, int N) {
  __shared__ float tile[32][33];
  const int n0 = blockIdx.x * 32, k0 = blockIdx.y * 32;
  const int tx = threadIdx.x, ty = threadIdx.y;  // 32 x 8
#pragma unroll
  for (int r = 0; r < 4; ++r)
    tile[ty + r * 8][tx] = W[(size_t)(k0 + ty + r * 8) * N + n0 + tx];
  __syncthreads();
#pragma unroll
  for (int r = 0; r < 4; ++r)
    WT[(size_t)(n0 + ty + r * 8) * K + k0 + tx] = (_Float16)tile[tx][ty + r * 8];
}

// ---------------- fp16 MFMA GEMM, 8-phase pipelined ----------------
// R10 change: 2-D supertile XCD swizzle. XCD x = bid&7 owns a compact RH x CW tile
// region; region grid is (8/RGC) x RGC. Per-XCD working set = RH A-panels + CW
// B-panels with RH/CW-fold in-region reuse (vs full-row B sweep) -> beyond-L2
// fetch ~halves. Mapping bijective.
template <int F16OUT, int NJ>
__global__ __launch_bounds__(512) void k_gemm256(const _Float16* __restrict__ A,
                                                 const _Float16* __restrict__ BT,
                                                 const float* __restrict__ bias,
                                                 void* __restrict__ Cout,
                                                 int M, int N, int K,
                                                 int RGC, int RH, int CW) {
  constexpr int BN = 64 * NJ;
  __shared__ __align__(16) _Float16 sA[2][256 * 64];
  __shared__ __align__(16) _Float16 sB[2][BN * 64];
  const int tid = threadIdx.x;
  const int lane = tid & 63;
  const int wid = tid >> 6;
  const int wr = wid >> 2;
  const int wc = wid & 3;
  const int lr = lane & 15;
  const int g = lane >> 4;
  const int rot = lr & 7;
  // supertile XCD swizzle
  const int bid = blockIdx.x;
  const int x = bid & 7, q = bid >> 3;
  const int bm = (x / RGC) * RH + q / CW;
  const int bn = (x % RGC) * CW + q % CW;
  const size_t arow0 = (size_t)bm * 256;
  const size_t brow0 = (size_t)bn * BN;

  f32x4 acc[8][NJ];
#pragma unroll
  for (int mi = 0; mi < 8; ++mi)
#pragma unroll
    for (int nj = 0; nj < NJ; ++nj) acc[mi][nj] = (f32x4){0.f, 0.f, 0.f, 0.f};

  auto STAGE_A = [&](int slot, int k0) {
#pragma unroll
    for (int r = 0; r < 4; ++r) {
      const int u = tid + r * 512;
      const int row = u >> 3, grl = u & 7;
      const int grn = (grl - (row & 7)) & 7;
      gload16(A + (arow0 + row) * K + k0 + grn * 8, &sA[slot][u * 8]);
    }
  };
  auto STAGE_B = [&](int slot, int k0) {
#pragma unroll
    for (int r = 0; r < NJ; ++r) {
      const int u = tid + r * 512;
      const int row = u >> 3, grl = u & 7;
      const int grn = (grl - (row & 7)) & 7;
      gload16(BT + (brow0 + row) * K + k0 + grn * 8, &sB[slot][u * 8]);
    }
  };

  f16x8 af[4], bf[NJ];
  auto LDA = [&](int slot, int mh, int kk) {
#pragma unroll
    for (int mi = 0; mi < 4; ++mi) {
      const int row = wr * 128 + (mh * 4 + mi) * 16 + lr;
      af[mi] = *(const f16x8*)&sA[slot][row * 64 + (((kk * 4 + g + rot) & 7) << 3)];
    }
  };
  auto LDB = [&](int slot, int kk) {
#pragma unroll
    for (int nj = 0; nj < NJ; ++nj) {
      const int row = wc * (16 * NJ) + nj * 16 + lr;
      bf[nj] = *(const f16x8*)&sB[slot][row * 64 + (((kk * 4 + g + rot) & 7) << 3)];
    }
  };
  auto MFMAB = [&](int mh) {
    __builtin_amdgcn_s_setprio(1);
#pragma unroll
    for (int mi = 0; mi < 4; ++mi)
#pragma unroll
      for (int nj = 0; nj < NJ; ++nj)
        acc[mh * 4 + mi][nj] =
            __builtin_amdgcn_mfma_f32_16x16x32_f16(af[mi], bf[nj], acc[mh * 4 + mi][nj], 0, 0, 0);
    __builtin_amdgcn_s_setprio(0);
    __builtin_amdgcn_sched_barrier(0);
  };

  STAGE_A(0, 0);
  STAGE_B(0, 0);
  asm volatile("s_waitcnt vmcnt(0)" ::: "memory");
  __builtin_amdgcn_s_barrier();

  const int NT = K >> 6;
  for (int t = 0; t < NT; ++t) {
    const int s = t & 1, ns = s ^ 1;
    const bool pf = (t + 1 < NT);
    const int kn = (t + 1) << 6;
    LDB(s, 0);
    LDA(s, 0, 0);
    if (pf) STAGE_A(ns, kn);
    __builtin_amdgcn_s_barrier();
    asm volatile("s_waitcnt lgkmcnt(0)" ::: "memory");
    __builtin_amdgcn_sched_barrier(0);
    MFMAB(0);
    __builtin_amdgcn_s_barrier();
    LDA(s, 1, 0);
    if (pf) STAGE_B(ns, kn);
    __builtin_amdgcn_s_barrier();
    asm volatile("s_waitcnt lgkmcnt(0)" ::: "memory");
    __builtin_amdgcn_sched_barrier(0);
    MFMAB(1);
    __builtin_amdgcn_s_barrier();
    LDB(s, 1);
    LDA(s, 0, 1);
    __builtin_amdgcn_s_barrier();
    asm volatile("s_waitcnt lgkmcnt(0)" ::: "memory");
    __builtin_amdgcn_sched_barrier(0);
    MFMAB(0);
    __builtin_amdgcn_s_barrier();
    LDA(s, 1, 1);
    __builtin_amdgcn_s_barrier();
    asm volatile("s_waitcnt lgkmcnt(0)" ::: "memory");
    __builtin_amdgcn_sched_barrier(0);
    MFMAB(1);
    asm volatile("s_waitcnt vmcnt(0)" ::: "memory");
    __builtin_amdgcn_s_barrier();
  }
  const size_t row0 = arow0 + wr * 128;
  const size_t col0 = brow0 + wc * (16 * NJ);
#pragma unroll
  for (int mi = 0; mi < 8; ++mi) {
#pragma unroll
    for (int nj = 0; nj < NJ; ++nj) {
      const size_t col = col0 + nj * 16 + lr;
      const float bv = bias[col];
#pragma unroll
      for (int r = 0; r < 4; ++r) {
        const size_t row = row0 + mi * 16 + g * 4 + r;
        const float v = acc[mi][nj][r] + bv;
        if (F16OUT)
          ((_Float16*)Cout)[row * N + col] = (_Float16)v;
        else
          ((float*)Cout)[row * N + col] = v;
      }
    }
  }
}

// ---------------- in-place RoPE on q,k sections of qkv (B,T,3C) fp16 ----------------
__global__ void k_rope(_Float16* __restrict__ qkv) {
  const int idx = blockIdx.x * blockDim.x + threadIdx.x;
  const int pp = idx & 2047;
  const int bt = idx >> 11;
  const int t = bt & (T_ - 1);
  const int sec = pp >> 10;
  const int p = pp & 1023;
  const int hh = p >> 6;
  const int dp = p & 63;
  const float freq = expf(-0.14391156831212787f * (float)dp);
  const float ang = (float)t * freq;
  float sn, cs;
  sincosf(ang, &sn, &cs);
  const size_t base = (size_t)bt * C3 + (size_t)sec * C_ + hh * D_ + 2 * dp;
  f16x2 v = *(f16x2*)(qkv + base);
  const float xe = (float)v.x, xo = (float)v.y;
  f16x2 o;
  o.x = (_Float16)(xe * cs - xo * sn);
  o.y = (_Float16)(xe * sn + xo * cs);
  *(f16x2*)(qkv + base) = o;
}

// ---------------- death time d[h][j]: index of 64th beater (T if <64 beaters) ----------------
__global__ __launch_bounds__(256) void k_death(const float* __restrict__ rw, int* __restrict__ dd) {
  const int widG = blockIdx.x * 4 + (threadIdx.x >> 6);
  const int lane = threadIdx.x & 63;
  const int h = widG >> 11, j = widG & (T_ - 1);
  const float* s = rw + h * T_;
  const float sj = s[j];
  int total = 0, d = T_;
  for (int base = 0; base < T_; base += 64) {
    const int t = base + lane;
    const float st = s[t];
    const bool beat = (st > sj) || (st == sj && t < j);
    const unsigned long long bal = __ballot(beat);
    const int c = __popcll(bal);
    if (total + c >= KSP) {
      const int need = KSP - total;
      const int p = __popcll(bal & ((1ull << lane) - 1ull));
      const unsigned long long win = __ballot(beat && (p == need - 1));
      d = base + __builtin_ctzll(win);
      break;
    }
    total += c;
  }
  if (lane == 0) dd[widG] = d;
}

// ---------------- superset key lists per (h, 16-query block) ----------------
// superset = {j <= i1 : d[h,j] > i0}, |.| <= 79 < 96. pk = j | (d<<12). pad pk=0 (self-masking).
__global__ __launch_bounds__(64) void k_slist(const int* __restrict__ dd,
                                              uint32_t* __restrict__ slist) {
  const int bid = blockIdx.x;  // h*128 + qb
  const int qb = bid & 127, h = bid >> 7;
  const int i0 = qb * 16, i1 = i0 + 15;
  const int lane = threadIdx.x;
  const int* dh = dd + h * T_;
  uint32_t* lb = slist + (size_t)bid * 96;
  int total = 0;
  for (int base = 0; base <= i1; base += 64) {
    const int j = base + lane;
    const int dv = dh[j];
    const bool pred = (j <= i1) && (dv > i0);
    const unsigned long long bal = __ballot(pred);
    const int pos = total + __popcll(bal & ((1ull << lane) - 1ull));
    if (pred) lb[pos] = (uint32_t)j | ((uint32_t)dv << 12);
    total += __popcll(bal);
  }
  for (int s = total + lane; s < 96; s += 64) lb[s] = 0;
}

// ---------------- MFMA sparse attention: one wave per (b, h, 16 queries) ----------------
__global__ __launch_bounds__(64, 4) void k_mattn(const _Float16* __restrict__ qkv,
                                                 const uint32_t* __restrict__ slist,
                                                 _Float16* __restrict__ out) {
  __shared__ uint32_t jd[96];
  __shared__ int joff[96];
  __shared__ __align__(16) _Float16 Pl[16 * 104];
  __shared__ __align__(16) _Float16 VT[2048];  // [mt4][lt16][gt4][e8] per (cc,dh) chunk
  const int bid = blockIdx.x;  // b*2048 + h*128 + qb
  const int qb = bid & 127, h = (bid >> 7) & 15, b = bid >> 11;
  const int i0 = qb * 16;
  const int lane = threadIdx.x;
  const int g = lane >> 4, l = lane & 15;
  const uint32_t* lb = slist + (size_t)((h << 7) + qb) * 96;
  {
    const uint32_t pk = lb[lane];
    jd[lane] = pk;
    joff[lane] = (int)(pk & 0xFFFu) * C3;
    if (lane < 32) {
      const uint32_t pk1 = lb[64 + lane];
      jd[64 + lane] = pk1;
      joff[64 + lane] = (int)(pk1 & 0xFFFu) * C3;
    }
  }
  __syncthreads();
  const _Float16* qkvb = qkv + (size_t)b * T_ * C3;
  // Q B-frags: lane gives Q[query=i0+l][dims 32c+8g+0..7]
  const _Float16* qrow = qkvb + (size_t)(i0 + l) * C3 + h * D_ + 8 * g;
  f16x8 bq[4];
#pragma unroll
  for (int c = 0; c < 4; ++c) bq[c] = *(const f16x8*)(qrow + 32 * c);
  // scores: per 16-slot tile t: A-frag = K[slot 16t+l][32c+8g..]
  f32x4 sacc[6];
  const _Float16* kbase = qkvb + C_ + h * D_ + 8 * g;
#pragma unroll
  for (int t = 0; t < 6; ++t) {
    const int jo = joff[16 * t + l];
    const _Float16* kr = kbase + jo;
    f16x8 ak[4];
#pragma unroll
    for (int c = 0; c < 4; ++c) ak[c] = *(const f16x8*)(kr + 32 * c);
    f32x4 a = {0.f, 0.f, 0.f, 0.f};
#pragma unroll
    for (int c = 0; c < 4; ++c)
      a = __builtin_amdgcn_mfma_f32_16x16x32_f16(ak[c], bq[c], a, 0, 0, 0);
    sacc[t] = a;  // S^T[slot 16t+4g+r][query i0+l]
  }
  // mask + softmax: lane's 24 values all belong to query iq = i0+l
  const int iq = i0 + l;
  float P[6][4];
  float m = -INFINITY;
#pragma unroll
  for (int t = 0; t < 6; ++t)
#pragma unroll
    for (int r = 0; r < 4; ++r) {
      const uint32_t pk = jd[16 * t + 4 * g + r];
      const int j = (int)(pk & 0xFFFu);
      const int d = (int)(pk >> 12);
      const bool ok = (j <= iq) && (d > iq);
      const float x = ok ? sacc[t][r] * 0.08838834764831845f : -INFINITY;
      P[t][r] = x;
      m = fmaxf(m, x);
    }
  m = fmaxf(m, __shfl_xor(m, 16));
  m = fmaxf(m, __shfl_xor(m, 32));
  float ssum = 0.f;
#pragma unroll
  for (int t = 0; t < 6; ++t)
#pragma unroll
    for (int r = 0; r < 4; ++r) {
      const float e = __expf(P[t][r] - m);
      P[t][r] = e;
      ssum += e;
    }
  ssum += __shfl_xor(ssum, 16);
  ssum += __shfl_xor(ssum, 32);
  const float inv = 1.0f / ssum;
  // P (f16, normalized) -> Pl[l][16t+4g+0..3]  (compiler fuses the casts to v_cvt_pkrtz)
#pragma unroll
  for (int t = 0; t < 6; ++t) {
    f16x4 w;
    w.x = (_Float16)(P[t][0] * inv);
    w.y = (_Float16)(P[t][1] * inv);
    w.z = (_Float16)(P[t][2] * inv);
    w.w = (_Float16)(P[t][3] * inv);
    *(f16x4*)&Pl[l * 104 + 16 * t + 4 * g] = w;
  }
  __syncthreads();
  // P A-frags: lane gives P[query=l][slots 32cc+8g+0..7]
  f16x8 pf[3];
#pragma unroll
  for (int cc = 0; cc < 3; ++cc) pf[cc] = *(const f16x8*)&Pl[l * 104 + 32 * cc + 8 * g];
  // PV
  f32x4 oacc[8];
#pragma unroll
  for (int mt = 0; mt < 8; ++mt) oacc[mt] = (f32x4){0.f, 0.f, 0.f, 0.f};
  const _Float16* vbase = qkvb + 2 * C_ + h * D_;
#pragma unroll
  for (int cc = 0; cc < 3; ++cc) {
    const int jo0 = joff[32 * cc + l];       // tau=0: slot 32cc+l
    const int jo1 = joff[32 * cc + 16 + l];  // tau=1: slot 32cc+16+l
#pragma unroll
    for (int dh = 0; dh < 2; ++dh) {
      f16x8 vl0[2], vl1[2];
#pragma unroll
      for (int cp = 0; cp < 2; ++cp) {
        vl0[cp] = *(const f16x8*)(vbase + jo0 + 64 * dh + 32 * cp + 8 * g);
        vl1[cp] = *(const f16x8*)(vbase + jo1 + 64 * dh + 32 * cp + 8 * g);
      }
      __syncthreads();  // previous chunk's reads complete before overwrite
      // scatter-transpose: element (slot=32cc+16tau+l, dim'=32cp+8g+e) ->
      //   VT[mt=2cp+(g>>1)][lt=8(g&1)+e][gt=2tau+(l>>3) ^ sigma][et=l&7], sigma==g here
#pragma unroll
      for (int tau = 0; tau < 2; ++tau)
#pragma unroll
        for (int cp = 0; cp < 2; ++cp) {
          const int mtl = 2 * cp + (g >> 1);
          const int lt0 = 8 * (g & 1);
          const int gt = (2 * tau + (l >> 3)) ^ g;
          const int et = l & 7;
#pragma unroll
          for (int e = 0; e < 8; ++e) {
            const int idx = ((mtl * 16 + lt0 + e) * 4 + gt) * 8 + et;
            VT[idx] = tau ? vl1[cp][e] : vl0[cp][e];
          }
        }
      __syncthreads();
      // V B-frags: lane gives V[slot 32cc+8g+e][dim 64dh+16mtl+l]
#pragma unroll
      for (int mtl = 0; mtl < 4; ++mtl) {
        const int sgr = (l >> 3) | ((mtl & 1) << 1);
        const f16x8 vf = *(const f16x8*)&VT[((mtl * 16 + l) * 4 + (g ^ sgr)) * 8];
        oacc[4 * dh + mtl] =
            __builtin_amdgcn_mfma_f32_16x16x32_f16(pf[cc], vf, oacc[4 * dh + mtl], 0, 0, 0);
      }
    }
  }
  // out[query i0+4g+r][h*128 + 16mt + l]
  _Float16* ob = out + (size_t)(b * T_ + i0 + 4 * g) * C_ + h * D_ + l;
#pragma unroll
  for (int mt = 0; mt < 8; ++mt)
#pragma unroll
    for (int r = 0; r < 4; ++r)
      ob[(size_t)r * C_ + 16 * mt] = (_Float16)oacc[mt][r];
}

extern "C" void kernel_launch(void* const* d_in, const int* in_sizes, int n_in,
                              void* d_out, int out_size, void* d_ws, size_t ws_size,
                              hipStream_t stream) {
  const float* x  = (const float*)d_in[0];
  const float* Wa = (const float*)d_in[1];
  const float* ba = (const float*)d_in[2];
  const float* Wp = (const float*)d_in[3];
  const float* bp = (const float*)d_in[4];
  const float* rw = (const float*)d_in[5];

  char* ws = (char*)d_ws;
  _Float16* qkv16 = (_Float16*)(ws);                              // 48 MB
  _Float16* WaT   = (_Float16*)(ws + (size_t)48 * 1024 * 1024);   // 24 MB
  _Float16* WpT   = (_Float16*)(ws + (size_t)72 * 1024 * 1024);   //  8 MB
  _Float16* x16   = (_Float16*)(ws + (size_t)80 * 1024 * 1024);   // 16 MB (reused as att16)
  int* dd  = (int*)(ws + (size_t)96 * 1024 * 1024);               // 128 KB
  uint32_t* slist = (uint32_t*)(ws + (size_t)96 * 1024 * 1024 + (2 << 17));  // 786 KB
  _Float16* att16 = x16;  // x16 dead after GEMM1

  // 1. x -> fp16
  k_cvt<<<dim3((B_ * T_ * C_) / 1024), dim3(256), 0, stream>>>(x, x16, B_ * T_ * C_);
  // 2. W_attn -> WaT fp16
  k_tconv<<<dim3(C3 / 32, C_ / 32), dim3(32, 8), 0, stream>>>(Wa, WaT, C_, C3);
  // 3. W_proj -> WpT fp16
  k_tconv<<<dim3(C_ / 32, C_ / 32), dim3(32, 8), 0, stream>>>(Wp, WpT, C_, C_);
  // 4. qkv = x @ W_attn + b_attn (fp16 out): grid 512; XCD regions 8x8 (RGC=4,RH=8,CW=8)
  k_gemm256<1, 3><<<dim3(512), dim3(512), 0, stream>>>(
      x16, WaT, ba, (void*)qkv16, B_ * T_, C3, C_, 4, 8, 8);
  // 5. RoPE in place on q,k
  k_rope<<<dim3((B_ * T_ * 2048) / 256), dim3(256), 0, stream>>>(qkv16);
  // 6. death times
  k_death<<<dim3(H_ * T_ / 4), dim3(256), 0, stream>>>(rw, dd);
  // 7. superset key lists per (h, 16-query block)
  k_slist<<<dim3(H_ * (T_ / 16)), dim3(64), 0, stream>>>(dd, slist);
  // 8. MFMA sparse attention -> att16
  k_mattn<<<dim3(B_ * H_ * (T_ / 16)), dim3(64), 0, stream>>>(qkv16, slist, att16);
  // 9. out = att @ W_proj + b_proj (f32 out): grid 256; XCD regions 8x4 (RGC=4,RH=8,CW=4)
  k_gemm256<0, 2><<<dim3(256), dim3(512), 0, stream>>>(
      att16, WpT, bp, d_out, B_ * T_, C_, C_, 4, 8, 4);
}